// Round 14
// baseline (859.207 us; speedup 1.0000x reference)
//
#include <hip/hip_runtime.h>
#include <hip/hip_bf16.h>
#include <math.h>

#define D     128
#define NHEAD 4
#define DH    32
#define DFF   512
#define DIN   16
#define MAXDEG 64
#define TN    16

typedef __attribute__((ext_vector_type(8))) short bf16x8;
typedef __attribute__((ext_vector_type(4))) float f32x4;
typedef __hip_bfloat16 bf16;

// 1/sqrt(32) * log2(e): q pre-scaled so attn weight = exp2(q.k)
#define QSCALE_L2E 0.2550348838f

// LDS row pad 132 bf16: C-layout scalar writes conflict-free (r9/r11).
// r10: register-prefetch of weight tiles spills — don't.
// r13: A-fragments in 16 VGPRs straight from global (per-wave rows) works.
// r13 lesson: k_ffn time invariant to occupancy/conflicts/barriers →
//             fixed per-dispatch cost → amortize by fusing dispatches (r14).
#define AP 132
#define BM 64

// ---------------- CSR build ----------------
__global__ void k_zero_int(int* p, int n) {
    int i = blockIdx.x * blockDim.x + threadIdx.x;
    if (i < n) p[i] = 0;
}

__global__ void k_fill(const int* __restrict__ recv, const int* __restrict__ senders,
                       int* __restrict__ deg, int* __restrict__ eid, int E) {
    int e = blockIdx.x * blockDim.x + threadIdx.x;
    if (e >= E) return;
    int r = recv[e];
    int pos = atomicAdd(&deg[r], 1);
    if (pos < MAXDEG) eid[r * MAXDEG + pos] = senders[e];
}

// ---------------- weight transpose + bf16 convert (one launch, 25 regions) ----
__global__ void k_wt(const float* __restrict__ wq, const float* __restrict__ wk,
                     const float* __restrict__ wv, const float* __restrict__ wo,
                     const float* __restrict__ w1, const float* __restrict__ w2,
                     const float* __restrict__ encw2,
                     bf16* __restrict__ wqkvT, bf16* __restrict__ woT,
                     bf16* __restrict__ w1T, bf16* __restrict__ w2T,
                     bf16* __restrict__ encw2T) {
    int r = blockIdx.y;
    const float* src; bf16* dst; int K, Nout;
    if (r < 12) {
        int l = r / 3, sel = r % 3;
        src = (sel == 0 ? wq : sel == 1 ? wk : wv) + (size_t)l * D * D;
        dst = wqkvT + (size_t)l * 3 * D * D + (size_t)sel * D * D;
        K = D; Nout = D;
    } else if (r < 16) {
        int l = r - 12;
        src = wo + (size_t)l * D * D; dst = woT + (size_t)l * D * D; K = D; Nout = D;
    } else if (r < 20) {
        int l = r - 16;
        src = w1 + (size_t)l * D * DFF; dst = w1T + (size_t)l * D * DFF; K = D; Nout = DFF;
    } else if (r < 24) {
        int l = r - 20;
        src = w2 + (size_t)l * DFF * D; dst = w2T + (size_t)l * DFF * D; K = DFF; Nout = D;
    } else {
        src = encw2; dst = encw2T; K = D; Nout = D;
    }
    int total = K * Nout;
    int i = blockIdx.x * blockDim.x + threadIdx.x;
    if (i >= total) return;
    int k = i / Nout, j = i % Nout;
    dst[(size_t)j * K + k] = __float2bfloat16(src[i]);
}

// helper: load this wave's 4 A-fragments (16 rows x 128 cols) from global
__device__ __forceinline__ void load_afrag(const bf16* A, int arow, int quad,
                                           int N, bf16x8* afr) {
    const bf16* ab = A + (size_t)arow * D + quad * 8;
#pragma unroll
    for (int i = 0; i < 4; i++) {
        uint4 v = make_uint4(0u, 0u, 0u, 0u);
        if (arow < N) v = *(const uint4*)(ab + i * 32);
        afr[i] = *(bf16x8*)&v;
    }
}

// ---------------- encoder GEMM: x = hb@encw2 + b2; hb = LN1_0(x) ------------
__global__ __launch_bounds__(256) void k_gemm5(
        const bf16* __restrict__ A, const bf16* __restrict__ Bt,
        const float* __restrict__ bias,
        const float* __restrict__ lns, const float* __restrict__ lnb,
        float* x, bf16* outB, int N) {
    __shared__ alignas(16) bf16 Wsm[128][AP];
    int m0 = blockIdx.x * BM;
    int t = threadIdx.x;
    int wave = t >> 6, lane = t & 63;
    int quad = lane >> 4, l16 = lane & 15;
    int wm = wave * 16;

    bf16x8 afr[4];
    load_afrag(A, m0 + wm + l16, quad, N, afr);
#pragma unroll
    for (int it = 0; it < 8; it++) {
        int ci = it * 256 + t;
        int rr = ci >> 4, cc = (ci & 15) * 8;
        *(uint4*)&Wsm[rr][cc] = *(const uint4*)(Bt + (size_t)rr * D + cc);
    }
    __syncthreads();

    f32x4 acc[8];
#pragma unroll
    for (int j = 0; j < 8; j++) acc[j] = (f32x4){0.f, 0.f, 0.f, 0.f};
#pragma unroll
    for (int i = 0; i < 4; i++) {
#pragma unroll
        for (int j = 0; j < 8; j++) {
            bf16x8 bfr = *(const bf16x8*)&Wsm[j * 16 + l16][i * 32 + quad * 8];
            acc[j] = __builtin_amdgcn_mfma_f32_16x16x32_bf16(afr[i], bfr, acc[j], 0, 0, 0);
        }
    }

    int rowb = m0 + wm + quad * 4;
    float bv[8], lsv[8], lbv[8];
#pragma unroll
    for (int j = 0; j < 8; j++) {
        bv[j]  = bias[j * 16 + l16];
        lsv[j] = lns[j * 16 + l16];
        lbv[j] = lnb[j * 16 + l16];
    }
#pragma unroll
    for (int j = 0; j < 8; j++)
#pragma unroll
        for (int r = 0; r < 4; r++) acc[j][r] += bv[j];
#pragma unroll
    for (int r = 0; r < 4; r++) {
        float s1 = 0.f, s2 = 0.f;
#pragma unroll
        for (int j = 0; j < 8; j++) {
            float v = acc[j][r];
            s1 += v; s2 += v * v;
        }
        s1 += __shfl_xor(s1, 1, 64);  s2 += __shfl_xor(s2, 1, 64);
        s1 += __shfl_xor(s1, 2, 64);  s2 += __shfl_xor(s2, 2, 64);
        s1 += __shfl_xor(s1, 4, 64);  s2 += __shfl_xor(s2, 4, 64);
        s1 += __shfl_xor(s1, 8, 64);  s2 += __shfl_xor(s2, 8, 64);
        float mu = s1 * (1.f / 128.f);
        float var = s2 * (1.f / 128.f) - mu * mu;
        float rinv = rsqrtf(fmaxf(var, 0.f) + 1e-5f);
        int gr = rowb + r;
        if (gr >= N) continue;
#pragma unroll
        for (int j = 0; j < 8; j++) {
            int col = j * 16 + l16;
            float v = acc[j][r];
            x[(size_t)gr * D + col] = v;
            outB[(size_t)gr * D + col] =
                __float2bfloat16((v - mu) * rinv * lsv[j] + lbv[j]);
        }
    }
}

// ---------------- fused QKV: A-frags in regs, weight tile in LDS ------------
__global__ __launch_bounds__(256) void k_qkv(
        const bf16* __restrict__ hb, const bf16* __restrict__ wqkvT,
        bf16* __restrict__ qb, bf16* __restrict__ kvb, int N) {
    __shared__ alignas(16) bf16 Wsm[128][AP];
    int m0 = blockIdx.x * BM;
    int t = threadIdx.x;
    int wave = t >> 6, lane = t & 63;
    int quad = lane >> 4, l16 = lane & 15;
    int wm = wave * 16;

    bf16x8 afr[4];
    load_afrag(hb, m0 + wm + l16, quad, N, afr);

    for (int y = 0; y < 3; y++) {
        const bf16* W = wqkvT + (size_t)y * D * D;
#pragma unroll
        for (int it = 0; it < 8; it++) {
            int ci = it * 256 + t;
            int rr = ci >> 4, cc = (ci & 15) * 8;
            *(uint4*)&Wsm[rr][cc] = *(const uint4*)(W + (size_t)rr * D + cc);
        }
        __syncthreads();

        f32x4 acc[8];
#pragma unroll
        for (int j = 0; j < 8; j++) acc[j] = (f32x4){0.f, 0.f, 0.f, 0.f};
#pragma unroll
        for (int i = 0; i < 4; i++) {
#pragma unroll
            for (int j = 0; j < 8; j++) {
                bf16x8 bfr = *(const bf16x8*)&Wsm[j * 16 + l16][i * 32 + quad * 8];
                acc[j] = __builtin_amdgcn_mfma_f32_16x16x32_bf16(afr[i], bfr, acc[j], 0, 0, 0);
            }
        }
        int rowb = m0 + wm + quad * 4;
#pragma unroll
        for (int j = 0; j < 8; j++) {
            int col = j * 16 + l16;
#pragma unroll
            for (int r = 0; r < 4; r++) {
                int gr = rowb + r;
                if (gr >= N) continue;
                float val = acc[j][r];
                if (y == 0) qb[(size_t)gr * D + col] = __float2bfloat16(val * QSCALE_L2E);
                else kvb[((size_t)gr * D + col) * 2 + (y - 1)] = __float2bfloat16(val);
            }
        }
        if (y < 2) __syncthreads();
    }
}

// ---------------- fused WO + LN2 + FFN [+ LN1_{l+1}] ------------------------
// ha = attn out (bf16). Computes: xm = x + ha@wo; h2 = LN2(xm) (via Hsm
// round-trip, xm kept in regs); x = xm + relu(h2@w1+b1)@w2 + b2;
// DOLN: hb = LN1next(x).  One dispatch replaces k_gemm<2> + k_ffn.
template<bool DOLN>
__global__ __launch_bounds__(256) void k_wo_ffn(
        const bf16* __restrict__ ha, const bf16* __restrict__ woT,
        const float* __restrict__ ln2s, const float* __restrict__ ln2b,
        const bf16* __restrict__ w1T, const float* __restrict__ b1,
        const bf16* __restrict__ w2T, const float* __restrict__ b2,
        const float* __restrict__ lns, const float* __restrict__ lnb,
        float* x, bf16* outB, int N) {
    __shared__ alignas(16) bf16 Wsm[128][AP];    // 33.8 KB (wo/W1c/W2c)
    __shared__ alignas(16) bf16 Hsm[64][AP];     // 16.9 KB (LN stripe, hidden)
    int m0 = blockIdx.x * 64;
    int t = threadIdx.x;
    int wave = t >> 6, lane = t & 63;
    int quad = lane >> 4, l16 = lane & 15;
    int wm = wave * 16;
    int rowb = m0 + wm + quad * 4;

    // ---- stage 1: wo GEMM ----
    bf16x8 afr[4];
    load_afrag(ha, m0 + wm + l16, quad, N, afr);
#pragma unroll
    for (int it = 0; it < 8; it++) {
        int ci = it * 256 + t;
        int rr = ci >> 4, cc = (ci & 15) * 8;
        *(uint4*)&Wsm[rr][cc] = *(const uint4*)(woT + (size_t)rr * D + cc);
    }
    __syncthreads();                              // s1: Wsm(wo) ready

    f32x4 accW[8];
#pragma unroll
    for (int j = 0; j < 8; j++) accW[j] = (f32x4){0.f, 0.f, 0.f, 0.f};
#pragma unroll
    for (int i = 0; i < 4; i++) {
#pragma unroll
        for (int j = 0; j < 8; j++) {
            bf16x8 bfr = *(const bf16x8*)&Wsm[j * 16 + l16][i * 32 + quad * 8];
            accW[j] = __builtin_amdgcn_mfma_f32_16x16x32_bf16(afr[i], bfr, accW[j], 0, 0, 0);
        }
    }
    __syncthreads();                              // s2: Wsm(wo) reads done

    // ---- stage 2: stage W1_0; xm = accW + x (regs); LN2 -> Hsm ----
#pragma unroll
    for (int it = 0; it < 8; it++) {
        int ci = it * 256 + t;
        int rr = ci >> 4, cc = (ci & 15) * 8;
        *(uint4*)&Wsm[rr][cc] = *(const uint4*)(w1T + (size_t)rr * D + cc);
    }
#pragma unroll
    for (int j = 0; j < 8; j++) {
        int col = j * 16 + l16;
#pragma unroll
        for (int r = 0; r < 4; r++) {
            int gr = rowb + r;
            if (gr < N) accW[j][r] += x[(size_t)gr * D + col];
        }
    }
    {
        float l2s[8], l2b[8];
#pragma unroll
        for (int j = 0; j < 8; j++) {
            l2s[j] = ln2s[j * 16 + l16];
            l2b[j] = ln2b[j * 16 + l16];
        }
#pragma unroll
        for (int r = 0; r < 4; r++) {
            float s1 = 0.f, s2 = 0.f;
#pragma unroll
            for (int j = 0; j < 8; j++) {
                float v = accW[j][r];
                s1 += v; s2 += v * v;
            }
            s1 += __shfl_xor(s1, 1, 64);  s2 += __shfl_xor(s2, 1, 64);
            s1 += __shfl_xor(s1, 2, 64);  s2 += __shfl_xor(s2, 2, 64);
            s1 += __shfl_xor(s1, 4, 64);  s2 += __shfl_xor(s2, 4, 64);
            s1 += __shfl_xor(s1, 8, 64);  s2 += __shfl_xor(s2, 8, 64);
            float mu = s1 * (1.f / 128.f);
            float var = s2 * (1.f / 128.f) - mu * mu;
            float rinv = rsqrtf(fmaxf(var, 0.f) + 1e-5f);
            int rw = wm + quad * 4 + r;
#pragma unroll
            for (int j = 0; j < 8; j++) {
                int col = j * 16 + l16;
                Hsm[rw][col] = __float2bfloat16(
                    (accW[j][r] - mu) * rinv * l2s[j] + l2b[j]);
            }
        }
    }
    __syncthreads();                              // s3: Wsm(W1_0) + Hsm ready

    // FFN A-frags from the LN2 stripe in LDS
#pragma unroll
    for (int i = 0; i < 4; i++)
        afr[i] = *(const bf16x8*)&Hsm[wm + l16][i * 32 + quad * 8];

    f32x4 acc2[8];
#pragma unroll
    for (int j = 0; j < 8; j++) acc2[j] = (f32x4){0.f, 0.f, 0.f, 0.f};

    for (int c = 0; c < 4; c++) {
        f32x4 accP[8];
#pragma unroll
        for (int j = 0; j < 8; j++) accP[j] = (f32x4){0.f, 0.f, 0.f, 0.f};
#pragma unroll
        for (int i = 0; i < 4; i++) {
#pragma unroll
            for (int j = 0; j < 8; j++) {
                bf16x8 bfr = *(const bf16x8*)&Wsm[j * 16 + l16][i * 32 + quad * 8];
                accP[j] = __builtin_amdgcn_mfma_f32_16x16x32_bf16(afr[i], bfr, accP[j], 0, 0, 0);
            }
        }
        __syncthreads();           // s4: Wsm(W1c) + (c==0: Hsm afr) reads done
#pragma unroll
        for (int it = 0; it < 8; it++) {
            int ci = it * 256 + t;
            int rr = ci >> 4, cc = (ci & 15) * 8;
            *(uint4*)&Wsm[rr][cc] = *(const uint4*)(w2T + (size_t)rr * DFF + c * 128 + cc);
        }
        {
            float bv[8];
#pragma unroll
            for (int j = 0; j < 8; j++) bv[j] = b1[c * 128 + j * 16 + l16];
            int rw = wm + quad * 4;
#pragma unroll
            for (int j = 0; j < 8; j++) {
                int col = j * 16 + l16;
#pragma unroll
                for (int r = 0; r < 4; r++)
                    Hsm[rw + r][col] = __float2bfloat16(fmaxf(accP[j][r] + bv[j], 0.f));
            }
        }
        __syncthreads();           // s5: Wsm(W2c) + Hsm(hidden c) ready
#pragma unroll
        for (int ks = 0; ks < 4; ks++) {
            bf16x8 af2 = *(const bf16x8*)&Hsm[wm + l16][ks * 32 + quad * 8];
#pragma unroll
            for (int j = 0; j < 8; j++) {
                bf16x8 bfr = *(const bf16x8*)&Wsm[j * 16 + l16][ks * 32 + quad * 8];
                acc2[j] = __builtin_amdgcn_mfma_f32_16x16x32_bf16(af2, bfr, acc2[j], 0, 0, 0);
            }
        }
        if (c < 3) {
            __syncthreads();       // s6: Wsm(W2c)/Hsm reads done
#pragma unroll
            for (int it = 0; it < 8; it++) {
                int ci = it * 256 + t;
                int rr = ci >> 4, cc = (ci & 15) * 8;
                *(uint4*)&Wsm[rr][cc] =
                    *(const uint4*)(w1T + (size_t)((c + 1) * 128 + rr) * D + cc);
            }
            __syncthreads();       // s7: Wsm(W1 next) ready
        }
    }

    // ---- epilogue: x = accW(xm, regs) + acc2 + b2; [LN1next -> outB] ----
    float bv[8];
#pragma unroll
    for (int j = 0; j < 8; j++) bv[j] = b2[j * 16 + l16];
#pragma unroll
    for (int j = 0; j < 8; j++)
#pragma unroll
        for (int r = 0; r < 4; r++)
            acc2[j][r] += accW[j][r] + bv[j];
    if (!DOLN) {
#pragma unroll
        for (int j = 0; j < 8; j++) {
            int col = j * 16 + l16;
#pragma unroll
            for (int r = 0; r < 4; r++) {
                int gr = rowb + r;
                if (gr < N) x[(size_t)gr * D + col] = acc2[j][r];
            }
        }
        return;
    }
    float lsv[8], lbv[8];
#pragma unroll
    for (int j = 0; j < 8; j++) {
        lsv[j] = lns[j * 16 + l16];
        lbv[j] = lnb[j * 16 + l16];
    }
#pragma unroll
    for (int r = 0; r < 4; r++) {
        float s1 = 0.f, s2 = 0.f;
#pragma unroll
        for (int j = 0; j < 8; j++) {
            float v = acc2[j][r];
            s1 += v; s2 += v * v;
        }
        s1 += __shfl_xor(s1, 1, 64);  s2 += __shfl_xor(s2, 1, 64);
        s1 += __shfl_xor(s1, 2, 64);  s2 += __shfl_xor(s2, 2, 64);
        s1 += __shfl_xor(s1, 4, 64);  s2 += __shfl_xor(s2, 4, 64);
        s1 += __shfl_xor(s1, 8, 64);  s2 += __shfl_xor(s2, 8, 64);
        float mu = s1 * (1.f / 128.f);
        float var = s2 * (1.f / 128.f) - mu * mu;
        float rinv = rsqrtf(fmaxf(var, 0.f) + 1e-5f);
        int gr = rowb + r;
        if (gr >= N) continue;
#pragma unroll
        for (int j = 0; j < 8; j++) {
            int col = j * 16 + l16;
            float v = acc2[j][r];
            x[(size_t)gr * D + col] = v;
            outB[(size_t)gr * D + col] = __float2bfloat16((v - mu) * rinv * lsv[j] + lbv[j]);
        }
    }
}

// ---------------- encoder stage 1: hb = bf16(relu(f@w1+b1)) ----------------
__global__ void k_enc1(const float* __restrict__ feat,
                       const float* __restrict__ w1, const float* __restrict__ b1,
                       bf16* __restrict__ hb, int N) {
    __shared__ float fsh[TN][DIN];
    int n0 = blockIdx.x * TN;
    int j = threadIdx.x;            // 0..127
    int nvalid = min(TN, N - n0);
    for (int idx = j; idx < TN * DIN; idx += 128) {
        int n = idx / DIN, i = idx % DIN;
        fsh[n][i] = (n < nvalid) ? feat[(n0 + n) * DIN + i] : 0.f;
    }
    __syncthreads();
    float bb = b1[j];
#pragma unroll
    for (int n = 0; n < TN; n++) {
        float a = bb;
#pragma unroll
        for (int i = 0; i < DIN; i++) a += fsh[n][i] * w1[i * D + j];
        if (n < nvalid) hb[(size_t)(n0 + n) * D + j] = __float2bfloat16(fmaxf(a, 0.f));
    }
}

// ---------------- fused per-receiver softmax attention (8-lane edge-head) ----
__global__ __launch_bounds__(128) void k_attn(
        const bf16* __restrict__ qb, const uint* __restrict__ kvb,
        const int* __restrict__ deg, const int* __restrict__ eid,
        bf16* __restrict__ out, int N) {
    __shared__ float sl[32], sa[32][4];
    int r = blockIdx.x;
    int t = threadIdx.x;
    int wave = t >> 6, lane = t & 63;
    int g = lane & 7;                    // dim group
    int h = (lane >> 3) & 3;             // head
    int slot = wave * 2 + (lane >> 5);   // edge slot 0..3
    int d0 = h * 32 + g * 4;
    uint2 qw = *(const uint2*)(qb + (size_t)r * D + d0);
    float4 qv;
    qv.x = __uint_as_float(qw.x << 16);
    qv.y = __uint_as_float(qw.x & 0xFFFF0000u);
    qv.z = __uint_as_float(qw.y << 16);
    qv.w = __uint_as_float(qw.y & 0xFFFF0000u);
    int cnt = min(deg[r], MAXDEG);
    const int* row = eid + (size_t)r * MAXDEG;
    float l = 0.f, a0 = 0.f, a1 = 0.f, a2 = 0.f, a3 = 0.f;
    for (int base = 0; base < cnt; base += 8) {
        int eiA = base + slot, eiB = base + 4 + slot;
        bool vA = eiA < cnt, vB = eiB < cnt;
        int sA = vA ? row[eiA] : 0;
        int sB = vB ? row[eiB] : 0;
        uint4 wA = *(const uint4*)(kvb + (size_t)sA * D + d0);
        uint4 wB = *(const uint4*)(kvb + (size_t)sB * D + d0);
        {
            float k0 = __uint_as_float(wA.x << 16), v0 = __uint_as_float(wA.x & 0xFFFF0000u);
            float k1 = __uint_as_float(wA.y << 16), v1 = __uint_as_float(wA.y & 0xFFFF0000u);
            float k2 = __uint_as_float(wA.z << 16), v2 = __uint_as_float(wA.z & 0xFFFF0000u);
            float k3 = __uint_as_float(wA.w << 16), v3 = __uint_as_float(wA.w & 0xFFFF0000u);
            float p = qv.x * k0 + qv.y * k1 + qv.z * k2 + qv.w * k3;
            p += __shfl_xor(p, 1, 64);
            p += __shfl_xor(p, 2, 64);
            p += __shfl_xor(p, 4, 64);
            float e = vA ? exp2f(p) : 0.f;
            l += e;
            a0 += e * v0; a1 += e * v1; a2 += e * v2; a3 += e * v3;
        }
        {
            float k0 = __uint_as_float(wB.x << 16), v0 = __uint_as_float(wB.x & 0xFFFF0000u);
            float k1 = __uint_as_float(wB.y << 16), v1 = __uint_as_float(wB.y & 0xFFFF0000u);
            float k2 = __uint_as_float(wB.z << 16), v2 = __uint_as_float(wB.z & 0xFFFF0000u);
            float k3 = __uint_as_float(wB.w << 16), v3 = __uint_as_float(wB.w & 0xFFFF0000u);
            float p = qv.x * k0 + qv.y * k1 + qv.z * k2 + qv.w * k3;
            p += __shfl_xor(p, 1, 64);
            p += __shfl_xor(p, 2, 64);
            p += __shfl_xor(p, 4, 64);
            float e = vB ? exp2f(p) : 0.f;
            l += e;
            a0 += e * v0; a1 += e * v1; a2 += e * v2; a3 += e * v3;
        }
    }
    l  += __shfl_xor(l, 32, 64);
    a0 += __shfl_xor(a0, 32, 64);
    a1 += __shfl_xor(a1, 32, 64);
    a2 += __shfl_xor(a2, 32, 64);
    a3 += __shfl_xor(a3, 32, 64);
    if (wave == 1 && lane < 32) {
        sl[lane] = l;
        sa[lane][0] = a0; sa[lane][1] = a1; sa[lane][2] = a2; sa[lane][3] = a3;
    }
    __syncthreads();
    if (wave == 0 && lane < 32) {
        l += sl[lane];
        float inv = 1.f / (l + 1e-9f);
        bf16 o[4];
        o[0] = __float2bfloat16((a0 + sa[lane][0]) * inv);
        o[1] = __float2bfloat16((a1 + sa[lane][1]) * inv);
        o[2] = __float2bfloat16((a2 + sa[lane][2]) * inv);
        o[3] = __float2bfloat16((a3 + sa[lane][3]) * inv);
        *(uint2*)(out + (size_t)r * D + d0) = *(uint2*)o;
    }
}

// ---------------- decoder: out = relu(x@w1+b1)@w2+b2, wave per node ----------
__global__ void k_decode(const float* __restrict__ x,
                         const float* __restrict__ w1, const float* __restrict__ b1,
                         const float* __restrict__ w2, const float* __restrict__ b2,
                         float* __restrict__ out, int N) {
    int node = blockIdx.x * 4 + (threadIdx.x >> 6);
    int lane = threadIdx.x & 63;
    if (node >= N) return;
    float a0 = x[(size_t)node * D + lane], a1 = x[(size_t)node * D + lane + 64];
    float acc0 = a0 * w1[lane * 3 + 0] + a1 * w1[(lane + 64) * 3 + 0];
    float acc1 = a0 * w1[lane * 3 + 1] + a1 * w1[(lane + 64) * 3 + 1];
    float acc2 = a0 * w1[lane * 3 + 2] + a1 * w1[(lane + 64) * 3 + 2];
#pragma unroll
    for (int m = 32; m >= 1; m >>= 1) {
        acc0 += __shfl_xor(acc0, m, 64);
        acc1 += __shfl_xor(acc1, m, 64);
        acc2 += __shfl_xor(acc2, m, 64);
    }
    if (lane == 0) {
        float t0 = fmaxf(acc0 + b1[0], 0.f);
        float t1 = fmaxf(acc1 + b1[1], 0.f);
        float t2 = fmaxf(acc2 + b1[2], 0.f);
        for (int o = 0; o < 3; o++)
            out[(size_t)node * 3 + o] =
                t0 * w2[0 * 3 + o] + t1 * w2[1 * 3 + o] + t2 * w2[2 * 3 + o] + b2[o];
    }
}

extern "C" void kernel_launch(void* const* d_in, const int* in_sizes, int n_in,
                              void* d_out, int out_size, void* d_ws, size_t ws_size,
                              hipStream_t stream) {
    const float* feat    = (const float*)d_in[0];
    const int*   senders = (const int*)d_in[1];
    const int*   recv    = (const int*)d_in[2];
    const float* enc_w1  = (const float*)d_in[3];
    const float* enc_b1  = (const float*)d_in[4];
    const float* enc_w2  = (const float*)d_in[5];
    const float* enc_b2  = (const float*)d_in[6];
    const float* wq      = (const float*)d_in[7];
    const float* wk      = (const float*)d_in[8];
    const float* wv      = (const float*)d_in[9];
    const float* wo      = (const float*)d_in[10];
    const float* ln1_s   = (const float*)d_in[11];
    const float* ln1_b   = (const float*)d_in[12];
    const float* ffn_w1  = (const float*)d_in[13];
    const float* ffn_b1  = (const float*)d_in[14];
    const float* ffn_w2  = (const float*)d_in[15];
    const float* ffn_b2  = (const float*)d_in[16];
    const float* ln2_s   = (const float*)d_in[17];
    const float* ln2_b   = (const float*)d_in[18];
    const float* dec_w1  = (const float*)d_in[19];
    const float* dec_b1  = (const float*)d_in[20];
    const float* dec_w2  = (const float*)d_in[21];
    const float* dec_b2  = (const float*)d_in[22];

    int N = in_sizes[0] / DIN;
    int E = in_sizes[1];

    // workspace layout
    char* p = (char*)d_ws;
    float* x   = (float*)p;  p += (size_t)N * D * 4;        // residual fp32
    bf16*  qb  = (bf16*)p;   p += (size_t)N * D * 2;        // q bf16 (pre-scaled)
    bf16*  kvb = (bf16*)p;   p += (size_t)N * D * 2 * 2;    // (k,v) bf16 interleaved
    bf16*  hb  = (bf16*)p;   p += (size_t)N * D * 2;        // LN out / attn out bf16
    int* deg   = (int*)p;    p += (size_t)N * 4;
    int* eid   = (int*)p;    p += (size_t)N * MAXDEG * 4;
    bf16* wqkvT  = (bf16*)p; p += (size_t)4 * 3 * D * D * 2;
    bf16* woT    = (bf16*)p; p += (size_t)4 * D * D * 2;
    bf16* w1T    = (bf16*)p; p += (size_t)4 * D * DFF * 2;
    bf16* w2T    = (bf16*)p; p += (size_t)4 * DFF * D * 2;
    bf16* encw2T = (bf16*)p; p += (size_t)D * D * 2;

    int gm = (N + BM - 1) / BM;   // 782

    k_wt<<<dim3(256, 25), 256, 0, stream>>>(wq, wk, wv, wo, ffn_w1, ffn_w2, enc_w2,
                                            wqkvT, woT, w1T, w2T, encw2T);
    k_zero_int<<<(N + 255) / 256, 256, 0, stream>>>(deg, N);
    k_fill<<<(E + 255) / 256, 256, 0, stream>>>(recv, senders, deg, eid, E);
    k_enc1<<<(N + TN - 1) / TN, 128, 0, stream>>>(feat, enc_w1, enc_b1, hb, N);
    k_gemm5<<<gm, 256, 0, stream>>>(hb, encw2T, enc_b2, ln1_s, ln1_b, x, hb, N);

    for (int l = 0; l < 4; l++) {
        k_qkv<<<gm, 256, 0, stream>>>(hb, wqkvT + (size_t)l * 3 * D * D, qb, kvb, N);
        k_attn<<<N, 128, 0, stream>>>(qb, (const uint*)kvb, deg, eid, hb, N);
        if (l < 3)
            k_wo_ffn<true><<<gm, 256, 0, stream>>>(
                hb, woT + (size_t)l * D * D, ln2_s + l * D, ln2_b + l * D,
                w1T + (size_t)l * D * DFF, ffn_b1 + l * DFF,
                w2T + (size_t)l * DFF * D, ffn_b2 + l * D,
                ln1_s + (l + 1) * D, ln1_b + (l + 1) * D, x, hb, N);
        else
            k_wo_ffn<false><<<gm, 256, 0, stream>>>(
                hb, woT + (size_t)l * D * D, ln2_s + l * D, ln2_b + l * D,
                w1T + (size_t)l * D * DFF, ffn_b1 + l * DFF,
                w2T + (size_t)l * DFF * D, ffn_b2 + l * D,
                nullptr, nullptr, x, nullptr, N);
    }
    k_decode<<<(N + 3) / 4, 256, 0, stream>>>(x, dec_w1, dec_b1, dec_w2, dec_b2,
                                              (float*)d_out, N);
}

// Round 15
// 754.064 us; speedup vs baseline: 1.1394x; 1.1394x over previous
//
#include <hip/hip_runtime.h>
#include <hip/hip_bf16.h>
#include <math.h>

#define D     128
#define NHEAD 4
#define DH    32
#define DFF   512
#define DIN   16
#define MAXDEG 64
#define TN    16

typedef __attribute__((ext_vector_type(8))) short bf16x8;
typedef __attribute__((ext_vector_type(4))) float f32x4;
typedef __hip_bfloat16 bf16;

// 1/sqrt(32) * log2(e): q pre-scaled so attn weight = exp2(q.k)
#define QSCALE_L2E 0.2550348838f

// LDS row pad 132 bf16: C-layout scalar writes conflict-free (r9/r11).
// r10: register-prefetch of weight tiles spills — don't.
// r13: A-fragments in 16 VGPRs straight from global works; best dense config.
// r14: wo+ffn mega-fusion REGRESSED (123 vs 100 µs) — dense chain is
//      latency-plateau'd; do not restructure it further.
#define AP 132
#define BM 64

// ---------------- CSR build ----------------
__global__ void k_zero_int(int* p, int n) {
    int i = blockIdx.x * blockDim.x + threadIdx.x;
    if (i < n) p[i] = 0;
}

__global__ void k_fill(const int* __restrict__ recv, const int* __restrict__ senders,
                       int* __restrict__ deg, int* __restrict__ eid, int E) {
    int e = blockIdx.x * blockDim.x + threadIdx.x;
    if (e >= E) return;
    int r = recv[e];
    int pos = atomicAdd(&deg[r], 1);
    if (pos < MAXDEG) eid[r * MAXDEG + pos] = senders[e];
}

// ---------------- weight transpose + bf16 convert (one launch, 25 regions) ----
__global__ void k_wt(const float* __restrict__ wq, const float* __restrict__ wk,
                     const float* __restrict__ wv, const float* __restrict__ wo,
                     const float* __restrict__ w1, const float* __restrict__ w2,
                     const float* __restrict__ encw2,
                     bf16* __restrict__ wqkvT, bf16* __restrict__ woT,
                     bf16* __restrict__ w1T, bf16* __restrict__ w2T,
                     bf16* __restrict__ encw2T) {
    int r = blockIdx.y;
    const float* src; bf16* dst; int K, Nout;
    if (r < 12) {
        int l = r / 3, sel = r % 3;
        src = (sel == 0 ? wq : sel == 1 ? wk : wv) + (size_t)l * D * D;
        dst = wqkvT + (size_t)l * 3 * D * D + (size_t)sel * D * D;
        K = D; Nout = D;
    } else if (r < 16) {
        int l = r - 12;
        src = wo + (size_t)l * D * D; dst = woT + (size_t)l * D * D; K = D; Nout = D;
    } else if (r < 20) {
        int l = r - 16;
        src = w1 + (size_t)l * D * DFF; dst = w1T + (size_t)l * D * DFF; K = D; Nout = DFF;
    } else if (r < 24) {
        int l = r - 20;
        src = w2 + (size_t)l * DFF * D; dst = w2T + (size_t)l * DFF * D; K = DFF; Nout = D;
    } else {
        src = encw2; dst = encw2T; K = D; Nout = D;
    }
    int total = K * Nout;
    int i = blockIdx.x * blockDim.x + threadIdx.x;
    if (i >= total) return;
    int k = i / Nout, j = i % Nout;
    dst[(size_t)j * K + k] = __float2bfloat16(src[i]);
}

// helper: load this wave's 4 A-fragments (16 rows x 128 cols) from global
__device__ __forceinline__ void load_afrag(const bf16* A, int arow, int quad,
                                           int N, bf16x8* afr) {
    const bf16* ab = A + (size_t)arow * D + quad * 8;
#pragma unroll
    for (int i = 0; i < 4; i++) {
        uint4 v = make_uint4(0u, 0u, 0u, 0u);
        if (arow < N) v = *(const uint4*)(ab + i * 32);
        afr[i] = *(bf16x8*)&v;
    }
}

// ---------------- bf16 MFMA GEMM, 64 rows x 128 cols, K=128, 1 barrier ------
// A-fragments in registers; only the weight tile (128x128) in LDS.
// OPs: 2 RES_LN (wo+ln2), 5 BIAS_LN (encode+ln1_0)
template<int OP>
__global__ __launch_bounds__(256) void k_gemm(
        const bf16* __restrict__ A, const bf16* __restrict__ Bt,
        const float* __restrict__ bias,
        const float* __restrict__ lns, const float* __restrict__ lnb,
        float* x, bf16* outB, int N) {
    __shared__ alignas(16) bf16 Wsm[128][AP];    // 33.8 KB -> 4 blocks/CU
    int m0 = blockIdx.x * BM;
    int t = threadIdx.x;
    int wave = t >> 6, lane = t & 63;
    int quad = lane >> 4, l16 = lane & 15;
    int wm = wave * 16;

    bf16x8 afr[4];
    load_afrag(A, m0 + wm + l16, quad, N, afr);
#pragma unroll
    for (int it = 0; it < 8; it++) {
        int ci = it * 256 + t;
        int rr = ci >> 4, cc = (ci & 15) * 8;
        *(uint4*)&Wsm[rr][cc] = *(const uint4*)(Bt + (size_t)rr * D + cc);
    }
    __syncthreads();

    f32x4 acc[8];
#pragma unroll
    for (int j = 0; j < 8; j++) acc[j] = (f32x4){0.f, 0.f, 0.f, 0.f};
#pragma unroll
    for (int i = 0; i < 4; i++) {
#pragma unroll
        for (int j = 0; j < 8; j++) {
            bf16x8 bfr = *(const bf16x8*)&Wsm[j * 16 + l16][i * 32 + quad * 8];
            acc[j] = __builtin_amdgcn_mfma_f32_16x16x32_bf16(afr[i], bfr, acc[j], 0, 0, 0);
        }
    }

    // epilogue: residual/bias combine + LN (C[row=quad*4+r][col=l16])
    int rowb = m0 + wm + quad * 4;
    float bv[8];
    if (OP == 5) {
#pragma unroll
        for (int j = 0; j < 8; j++) bv[j] = bias[j * 16 + l16];
    }
#pragma unroll
    for (int j = 0; j < 8; j++) {
        int col = j * 16 + l16;
#pragma unroll
        for (int r = 0; r < 4; r++) {
            int gr = rowb + r;
            if (gr >= N) continue;
            float val = acc[j][r];
            if (OP == 5) val += bv[j];
            if (OP == 2) val += x[(size_t)gr * D + col];
            acc[j][r] = val;
        }
    }
    float lsv[8], lbv[8];
#pragma unroll
    for (int j = 0; j < 8; j++) {
        lsv[j] = lns[j * 16 + l16];
        lbv[j] = lnb[j * 16 + l16];
    }
#pragma unroll
    for (int r = 0; r < 4; r++) {
        float s1 = 0.f, s2 = 0.f;
#pragma unroll
        for (int j = 0; j < 8; j++) {
            float v = acc[j][r];
            s1 += v; s2 += v * v;
        }
        s1 += __shfl_xor(s1, 1, 64);  s2 += __shfl_xor(s2, 1, 64);
        s1 += __shfl_xor(s1, 2, 64);  s2 += __shfl_xor(s2, 2, 64);
        s1 += __shfl_xor(s1, 4, 64);  s2 += __shfl_xor(s2, 4, 64);
        s1 += __shfl_xor(s1, 8, 64);  s2 += __shfl_xor(s2, 8, 64);
        float mu = s1 * (1.f / 128.f);
        float var = s2 * (1.f / 128.f) - mu * mu;
        float rinv = rsqrtf(fmaxf(var, 0.f) + 1e-5f);
        int gr = rowb + r;
        if (gr >= N) continue;
#pragma unroll
        for (int j = 0; j < 8; j++) {
            int col = j * 16 + l16;
            float v = acc[j][r];
            x[(size_t)gr * D + col] = v;
            outB[(size_t)gr * D + col] =
                __float2bfloat16((v - mu) * rinv * lsv[j] + lbv[j]);
        }
    }
}

// ---------------- fused QKV: A-frags in regs, weight tile in LDS ------------
__global__ __launch_bounds__(256) void k_qkv(
        const bf16* __restrict__ hb, const bf16* __restrict__ wqkvT,
        bf16* __restrict__ qb, bf16* __restrict__ kvb, int N) {
    __shared__ alignas(16) bf16 Wsm[128][AP];    // 33.8 KB -> 4 blocks/CU
    int m0 = blockIdx.x * BM;
    int t = threadIdx.x;
    int wave = t >> 6, lane = t & 63;
    int quad = lane >> 4, l16 = lane & 15;
    int wm = wave * 16;

    bf16x8 afr[4];
    load_afrag(hb, m0 + wm + l16, quad, N, afr);

    for (int y = 0; y < 3; y++) {
        const bf16* W = wqkvT + (size_t)y * D * D;
#pragma unroll
        for (int it = 0; it < 8; it++) {
            int ci = it * 256 + t;
            int rr = ci >> 4, cc = (ci & 15) * 8;
            *(uint4*)&Wsm[rr][cc] = *(const uint4*)(W + (size_t)rr * D + cc);
        }
        __syncthreads();

        f32x4 acc[8];
#pragma unroll
        for (int j = 0; j < 8; j++) acc[j] = (f32x4){0.f, 0.f, 0.f, 0.f};
#pragma unroll
        for (int i = 0; i < 4; i++) {
#pragma unroll
            for (int j = 0; j < 8; j++) {
                bf16x8 bfr = *(const bf16x8*)&Wsm[j * 16 + l16][i * 32 + quad * 8];
                acc[j] = __builtin_amdgcn_mfma_f32_16x16x32_bf16(afr[i], bfr, acc[j], 0, 0, 0);
            }
        }
        int rowb = m0 + wm + quad * 4;
#pragma unroll
        for (int j = 0; j < 8; j++) {
            int col = j * 16 + l16;
#pragma unroll
            for (int r = 0; r < 4; r++) {
                int gr = rowb + r;
                if (gr >= N) continue;
                float val = acc[j][r];
                if (y == 0) qb[(size_t)gr * D + col] = __float2bfloat16(val * QSCALE_L2E);
                else kvb[((size_t)gr * D + col) * 2 + (y - 1)] = __float2bfloat16(val);
            }
        }
        if (y < 2) __syncthreads();
    }
}

// ---------------- fused FFN: x += relu(hb@w1+b1)@w2 + b2 [; LN -> hb] --------
// A-frags in regs (GEMM1); Wsm (33.8K) + Hsm (16.9K) = 50.7 KB -> 3 blocks/CU.
template<bool DOLN>
__global__ __launch_bounds__(256) void k_ffn(
        const bf16* __restrict__ hb, const bf16* __restrict__ w1T,
        const float* __restrict__ b1,
        const bf16* __restrict__ w2T, const float* __restrict__ b2,
        const float* __restrict__ lns, const float* __restrict__ lnb,
        float* x, bf16* outB, int N) {
    __shared__ alignas(16) bf16 Wsm[128][AP];    // 33.8 KB (W1c / W2c)
    __shared__ alignas(16) bf16 Hsm[64][AP];     // 16.9 KB
    int m0 = blockIdx.x * 64;
    int t = threadIdx.x;
    int wave = t >> 6, lane = t & 63;
    int quad = lane >> 4, l16 = lane & 15;
    int wm = wave * 16;

    bf16x8 afr[4];
    load_afrag(hb, m0 + wm + l16, quad, N, afr);
#pragma unroll
    for (int it = 0; it < 8; it++) {
        int ci = it * 256 + t;
        int rr = ci >> 4, cc = (ci & 15) * 8;
        *(uint4*)&Wsm[rr][cc] = *(const uint4*)(w1T + (size_t)rr * D + cc);
    }
    __syncthreads();

    f32x4 acc2[8];
#pragma unroll
    for (int j = 0; j < 8; j++) acc2[j] = (f32x4){0.f, 0.f, 0.f, 0.f};

    for (int c = 0; c < 4; c++) {
        // P = A @ W1c (A from registers)
        f32x4 accP[8];
#pragma unroll
        for (int j = 0; j < 8; j++) accP[j] = (f32x4){0.f, 0.f, 0.f, 0.f};
#pragma unroll
        for (int i = 0; i < 4; i++) {
#pragma unroll
            for (int j = 0; j < 8; j++) {
                bf16x8 bfr = *(const bf16x8*)&Wsm[j * 16 + l16][i * 32 + quad * 8];
                accP[j] = __builtin_amdgcn_mfma_f32_16x16x32_bf16(afr[i], bfr, accP[j], 0, 0, 0);
            }
        }
        __syncthreads();   // Wsm(W1c) reads done; prev Hsm reads done
        // stage W2c + write Hsm = relu(P + b1)
#pragma unroll
        for (int it = 0; it < 8; it++) {
            int ci = it * 256 + t;
            int rr = ci >> 4, cc = (ci & 15) * 8;
            *(uint4*)&Wsm[rr][cc] = *(const uint4*)(w2T + (size_t)rr * DFF + c * 128 + cc);
        }
        {
            float bv[8];
#pragma unroll
            for (int j = 0; j < 8; j++) bv[j] = b1[c * 128 + j * 16 + l16];
            int rw = wm + quad * 4;
#pragma unroll
            for (int j = 0; j < 8; j++) {
                int col = j * 16 + l16;
#pragma unroll
                for (int r = 0; r < 4; r++)
                    Hsm[rw + r][col] = __float2bfloat16(fmaxf(accP[j][r] + bv[j], 0.f));
            }
        }
        __syncthreads();
        // acc2 += Hsm @ W2c
#pragma unroll
        for (int ks = 0; ks < 4; ks++) {
            bf16x8 af2 = *(const bf16x8*)&Hsm[wm + l16][ks * 32 + quad * 8];
#pragma unroll
            for (int j = 0; j < 8; j++) {
                bf16x8 bfr = *(const bf16x8*)&Wsm[j * 16 + l16][ks * 32 + quad * 8];
                acc2[j] = __builtin_amdgcn_mfma_f32_16x16x32_bf16(af2, bfr, acc2[j], 0, 0, 0);
            }
        }
        if (c < 3) {
            __syncthreads();   // Wsm(W2c) reads done
#pragma unroll
            for (int it = 0; it < 8; it++) {
                int ci = it * 256 + t;
                int rr = ci >> 4, cc = (ci & 15) * 8;
                *(uint4*)&Wsm[rr][cc] =
                    *(const uint4*)(w1T + (size_t)((c + 1) * 128 + rr) * D + cc);
            }
            __syncthreads();
        }
    }

    // epilogue: out = acc2 + b2 + x; [LN -> outB]; store x
    int rowb = m0 + wm + quad * 4;
    float bv[8];
#pragma unroll
    for (int j = 0; j < 8; j++) bv[j] = b2[j * 16 + l16];
#pragma unroll
    for (int j = 0; j < 8; j++) {
        int col = j * 16 + l16;
#pragma unroll
        for (int r = 0; r < 4; r++) {
            int gr = rowb + r;
            if (gr >= N) continue;
            acc2[j][r] += bv[j] + x[(size_t)gr * D + col];
        }
    }
    if (!DOLN) {
#pragma unroll
        for (int j = 0; j < 8; j++) {
            int col = j * 16 + l16;
#pragma unroll
            for (int r = 0; r < 4; r++) {
                int gr = rowb + r;
                if (gr < N) x[(size_t)gr * D + col] = acc2[j][r];
            }
        }
        return;
    }
    float lsv[8], lbv[8];
#pragma unroll
    for (int j = 0; j < 8; j++) {
        lsv[j] = lns[j * 16 + l16];
        lbv[j] = lnb[j * 16 + l16];
    }
#pragma unroll
    for (int r = 0; r < 4; r++) {
        float s1 = 0.f, s2 = 0.f;
#pragma unroll
        for (int j = 0; j < 8; j++) {
            float v = acc2[j][r];
            s1 += v; s2 += v * v;
        }
        s1 += __shfl_xor(s1, 1, 64);  s2 += __shfl_xor(s2, 1, 64);
        s1 += __shfl_xor(s1, 2, 64);  s2 += __shfl_xor(s2, 2, 64);
        s1 += __shfl_xor(s1, 4, 64);  s2 += __shfl_xor(s2, 4, 64);
        s1 += __shfl_xor(s1, 8, 64);  s2 += __shfl_xor(s2, 8, 64);
        float mu = s1 * (1.f / 128.f);
        float var = s2 * (1.f / 128.f) - mu * mu;
        float rinv = rsqrtf(fmaxf(var, 0.f) + 1e-5f);
        int gr = rowb + r;
        if (gr >= N) continue;
#pragma unroll
        for (int j = 0; j < 8; j++) {
            int col = j * 16 + l16;
            float v = acc2[j][r];
            x[(size_t)gr * D + col] = v;
            outB[(size_t)gr * D + col] = __float2bfloat16((v - mu) * rinv * lsv[j] + lbv[j]);
        }
    }
}

// ---------------- encoder stage 1: hb = bf16(relu(f@w1+b1)) ----------------
__global__ void k_enc1(const float* __restrict__ feat,
                       const float* __restrict__ w1, const float* __restrict__ b1,
                       bf16* __restrict__ hb, int N) {
    __shared__ float fsh[TN][DIN];
    int n0 = blockIdx.x * TN;
    int j = threadIdx.x;            // 0..127
    int nvalid = min(TN, N - n0);
    for (int idx = j; idx < TN * DIN; idx += 128) {
        int n = idx / DIN, i = idx % DIN;
        fsh[n][i] = (n < nvalid) ? feat[(n0 + n) * DIN + i] : 0.f;
    }
    __syncthreads();
    float bb = b1[j];
#pragma unroll
    for (int n = 0; n < TN; n++) {
        float a = bb;
#pragma unroll
        for (int i = 0; i < DIN; i++) a += fsh[n][i] * w1[i * D + j];
        if (n < nvalid) hb[(size_t)(n0 + n) * D + j] = __float2bfloat16(fmaxf(a, 0.f));
    }
}

// ---------------- attention: ONE WAVE PER RECEIVER (no LDS, no barrier) -----
// 256-thread block = 4 waves = 4 receivers. Within a wave: slot = lane>>5
// (2 edge slots), head = (lane>>3)&3, dim group = lane&7 (4 dims via uint4).
// 4 edges per iteration (2 slots x A/B unroll); slot-combine = 1 shfl_xor(32).
__global__ __launch_bounds__(256) void k_attn(
        const bf16* __restrict__ qb, const uint* __restrict__ kvb,
        const int* __restrict__ deg, const int* __restrict__ eid,
        bf16* __restrict__ out, int N) {
    int wave = threadIdx.x >> 6, lane = threadIdx.x & 63;
    int r = blockIdx.x * 4 + wave;
    if (r >= N) return;
    int g = lane & 7;                    // dim group
    int h = (lane >> 3) & 3;             // head
    int slot = lane >> 5;                // edge slot 0..1
    int d0 = h * 32 + g * 4;
    uint2 qw = *(const uint2*)(qb + (size_t)r * D + d0);
    float4 qv;
    qv.x = __uint_as_float(qw.x << 16);
    qv.y = __uint_as_float(qw.x & 0xFFFF0000u);
    qv.z = __uint_as_float(qw.y << 16);
    qv.w = __uint_as_float(qw.y & 0xFFFF0000u);
    int cnt = min(deg[r], MAXDEG);
    const int* row = eid + (size_t)r * MAXDEG;
    float l = 0.f, a0 = 0.f, a1 = 0.f, a2 = 0.f, a3 = 0.f;
    for (int base = 0; base < cnt; base += 4) {
        int eiA = base + slot, eiB = base + 2 + slot;
        bool vA = eiA < cnt, vB = eiB < cnt;
        int sA = vA ? row[eiA] : 0;
        int sB = vB ? row[eiB] : 0;
        uint4 wA = *(const uint4*)(kvb + (size_t)sA * D + d0);
        uint4 wB = *(const uint4*)(kvb + (size_t)sB * D + d0);
        {
            float k0 = __uint_as_float(wA.x << 16), v0 = __uint_as_float(wA.x & 0xFFFF0000u);
            float k1 = __uint_as_float(wA.y << 16), v1 = __uint_as_float(wA.y & 0xFFFF0000u);
            float k2 = __uint_as_float(wA.z << 16), v2 = __uint_as_float(wA.z & 0xFFFF0000u);
            float k3 = __uint_as_float(wA.w << 16), v3 = __uint_as_float(wA.w & 0xFFFF0000u);
            float p = qv.x * k0 + qv.y * k1 + qv.z * k2 + qv.w * k3;
            p += __shfl_xor(p, 1, 64);
            p += __shfl_xor(p, 2, 64);
            p += __shfl_xor(p, 4, 64);
            float e = vA ? exp2f(p) : 0.f;
            l += e;
            a0 += e * v0; a1 += e * v1; a2 += e * v2; a3 += e * v3;
        }
        {
            float k0 = __uint_as_float(wB.x << 16), v0 = __uint_as_float(wB.x & 0xFFFF0000u);
            float k1 = __uint_as_float(wB.y << 16), v1 = __uint_as_float(wB.y & 0xFFFF0000u);
            float k2 = __uint_as_float(wB.z << 16), v2 = __uint_as_float(wB.z & 0xFFFF0000u);
            float k3 = __uint_as_float(wB.w << 16), v3 = __uint_as_float(wB.w & 0xFFFF0000u);
            float p = qv.x * k0 + qv.y * k1 + qv.z * k2 + qv.w * k3;
            p += __shfl_xor(p, 1, 64);
            p += __shfl_xor(p, 2, 64);
            p += __shfl_xor(p, 4, 64);
            float e = vB ? exp2f(p) : 0.f;
            l += e;
            a0 += e * v0; a1 += e * v1; a2 += e * v2; a3 += e * v3;
        }
    }
    // combine the 2 edge slots (lane bit 5)
    l  += __shfl_xor(l, 32, 64);
    a0 += __shfl_xor(a0, 32, 64);
    a1 += __shfl_xor(a1, 32, 64);
    a2 += __shfl_xor(a2, 32, 64);
    a3 += __shfl_xor(a3, 32, 64);
    if (lane < 32) {
        float inv = 1.f / (l + 1e-9f);
        bf16 o[4];
        o[0] = __float2bfloat16(a0 * inv);
        o[1] = __float2bfloat16(a1 * inv);
        o[2] = __float2bfloat16(a2 * inv);
        o[3] = __float2bfloat16(a3 * inv);
        *(uint2*)(out + (size_t)r * D + d0) = *(uint2*)o;
    }
}

// ---------------- decoder: out = relu(x@w1+b1)@w2+b2, wave per node ----------
__global__ void k_decode(const float* __restrict__ x,
                         const float* __restrict__ w1, const float* __restrict__ b1,
                         const float* __restrict__ w2, const float* __restrict__ b2,
                         float* __restrict__ out, int N) {
    int node = blockIdx.x * 4 + (threadIdx.x >> 6);
    int lane = threadIdx.x & 63;
    if (node >= N) return;
    float a0 = x[(size_t)node * D + lane], a1 = x[(size_t)node * D + lane + 64];
    float acc0 = a0 * w1[lane * 3 + 0] + a1 * w1[(lane + 64) * 3 + 0];
    float acc1 = a0 * w1[lane * 3 + 1] + a1 * w1[(lane + 64) * 3 + 1];
    float acc2 = a0 * w1[lane * 3 + 2] + a1 * w1[(lane + 64) * 3 + 2];
#pragma unroll
    for (int m = 32; m >= 1; m >>= 1) {
        acc0 += __shfl_xor(acc0, m, 64);
        acc1 += __shfl_xor(acc1, m, 64);
        acc2 += __shfl_xor(acc2, m, 64);
    }
    if (lane == 0) {
        float t0 = fmaxf(acc0 + b1[0], 0.f);
        float t1 = fmaxf(acc1 + b1[1], 0.f);
        float t2 = fmaxf(acc2 + b1[2], 0.f);
        for (int o = 0; o < 3; o++)
            out[(size_t)node * 3 + o] =
                t0 * w2[0 * 3 + o] + t1 * w2[1 * 3 + o] + t2 * w2[2 * 3 + o] + b2[o];
    }
}

extern "C" void kernel_launch(void* const* d_in, const int* in_sizes, int n_in,
                              void* d_out, int out_size, void* d_ws, size_t ws_size,
                              hipStream_t stream) {
    const float* feat    = (const float*)d_in[0];
    const int*   senders = (const int*)d_in[1];
    const int*   recv    = (const int*)d_in[2];
    const float* enc_w1  = (const float*)d_in[3];
    const float* enc_b1  = (const float*)d_in[4];
    const float* enc_w2  = (const float*)d_in[5];
    const float* enc_b2  = (const float*)d_in[6];
    const float* wq      = (const float*)d_in[7];
    const float* wk      = (const float*)d_in[8];
    const float* wv      = (const float*)d_in[9];
    const float* wo      = (const float*)d_in[10];
    const float* ln1_s   = (const float*)d_in[11];
    const float* ln1_b   = (const float*)d_in[12];
    const float* ffn_w1  = (const float*)d_in[13];
    const float* ffn_b1  = (const float*)d_in[14];
    const float* ffn_w2  = (const float*)d_in[15];
    const float* ffn_b2  = (const float*)d_in[16];
    const float* ln2_s   = (const float*)d_in[17];
    const float* ln2_b   = (const float*)d_in[18];
    const float* dec_w1  = (const float*)d_in[19];
    const float* dec_b1  = (const float*)d_in[20];
    const float* dec_w2  = (const float*)d_in[21];
    const float* dec_b2  = (const float*)d_in[22];

    int N = in_sizes[0] / DIN;
    int E = in_sizes[1];

    // workspace layout
    char* p = (char*)d_ws;
    float* x   = (float*)p;  p += (size_t)N * D * 4;        // residual fp32
    bf16*  qb  = (bf16*)p;   p += (size_t)N * D * 2;        // q bf16 (pre-scaled)
    bf16*  kvb = (bf16*)p;   p += (size_t)N * D * 2 * 2;    // (k,v) bf16 interleaved
    bf16*  hb  = (bf16*)p;   p += (size_t)N * D * 2;        // LN out / attn out bf16
    int* deg   = (int*)p;    p += (size_t)N * 4;
    int* eid   = (int*)p;    p += (size_t)N * MAXDEG * 4;
    bf16* wqkvT  = (bf16*)p; p += (size_t)4 * 3 * D * D * 2;
    bf16* woT    = (bf16*)p; p += (size_t)4 * D * D * 2;
    bf16* w1T    = (bf16*)p; p += (size_t)4 * D * DFF * 2;
    bf16* w2T    = (bf16*)p; p += (size_t)4 * DFF * D * 2;
    bf16* encw2T = (bf16*)p; p += (size_t)D * D * 2;

    int gm = (N + BM - 1) / BM;   // 782

    k_wt<<<dim3(256, 25), 256, 0, stream>>>(wq, wk, wv, wo, ffn_w1, ffn_w2, enc_w2,
                                            wqkvT, woT, w1T, w2T, encw2T);
    k_zero_int<<<(N + 255) / 256, 256, 0, stream>>>(deg, N);
    k_fill<<<(E + 255) / 256, 256, 0, stream>>>(recv, senders, deg, eid, E);
    k_enc1<<<(N + TN - 1) / TN, 128, 0, stream>>>(feat, enc_w1, enc_b1, hb, N);
    // x = hb @ enc_w2 + b2; hb = LN1_0(x)
    k_gemm<5><<<gm, 256, 0, stream>>>(hb, encw2T, enc_b2, ln1_s, ln1_b, x, hb, N);

    for (int l = 0; l < 4; l++) {
        k_qkv<<<gm, 256, 0, stream>>>(hb, wqkvT + (size_t)l * 3 * D * D, qb, kvb, N);
        k_attn<<<(N + 3) / 4, 256, 0, stream>>>(qb, (const uint*)kvb, deg, eid, hb, N);
        // x += hb @ wo; hb = LN2(x)
        k_gemm<2><<<gm, 256, 0, stream>>>(hb, woT + (size_t)l * D * D,
                                          nullptr, ln2_s + l * D, ln2_b + l * D,
                                          x, hb, N);
        // x += relu(hb@w1+b1)@w2 + b2; [LN1_{l+1} -> hb]
        if (l < 3)
            k_ffn<true><<<gm, 256, 0, stream>>>(hb, w1T + (size_t)l * D * DFF,
                                                ffn_b1 + l * DFF,
                                                w2T + (size_t)l * DFF * D, ffn_b2 + l * D,
                                                ln1_s + (l + 1) * D, ln1_b + (l + 1) * D,
                                                x, hb, N);
        else
            k_ffn<false><<<gm, 256, 0, stream>>>(hb, w1T + (size_t)l * D * DFF,
                                                 ffn_b1 + l * DFF,
                                                 w2T + (size_t)l * DFF * D, ffn_b2 + l * D,
                                                 nullptr, nullptr, x, nullptr, N);
    }
    k_decode<<<(N + 3) / 4, 256, 0, stream>>>(x, dec_w1, dec_b1, dec_w2, dec_b2,
                                              (float*)d_out, N);
}

// Round 16
// 732.264 us; speedup vs baseline: 1.1734x; 1.0298x over previous
//
#include <hip/hip_runtime.h>
#include <hip/hip_bf16.h>
#include <math.h>

#define D     128
#define NHEAD 4
#define DH    32
#define DFF   512
#define DIN   16
#define MAXDEG 64
#define TN    16

typedef __attribute__((ext_vector_type(8))) short bf16x8;
typedef __attribute__((ext_vector_type(4))) float f32x4;
typedef __hip_bfloat16 bf16;

// 1/sqrt(32) * log2(e): q pre-scaled so attn weight = exp2(q.k)
#define QSCALE_L2E 0.2550348838f

// LDS row pad 132 bf16: C-layout scalar writes conflict-free (r9/r11).
// r10: register-prefetch of weight tiles spills — don't.
// r13: A-fragments in 16 VGPRs straight from global; best dense config.
// r14: wo+ffn mega-fusion REGRESSED — dense chain is latency-plateau'd.
// r16: only remove dispatches/traffic outside the plateau'd inner loops.
#define AP 132
#define BM 64

// ---------------- CSR fill (deg zeroed by k_wt region 25) ----------------
__global__ void k_fill(const int* __restrict__ recv, const int* __restrict__ senders,
                       int* __restrict__ deg, int* __restrict__ eid, int E) {
    int e = blockIdx.x * blockDim.x + threadIdx.x;
    if (e >= E) return;
    int r = recv[e];
    int pos = atomicAdd(&deg[r], 1);
    if (pos < MAXDEG) eid[r * MAXDEG + pos] = senders[e];
}

// ---------------- weight transpose + bf16 convert + deg zero (26 regions) ----
__global__ void k_wt(const float* __restrict__ wq, const float* __restrict__ wk,
                     const float* __restrict__ wv, const float* __restrict__ wo,
                     const float* __restrict__ w1, const float* __restrict__ w2,
                     const float* __restrict__ encw2,
                     bf16* __restrict__ wqkvT, bf16* __restrict__ woT,
                     bf16* __restrict__ w1T, bf16* __restrict__ w2T,
                     bf16* __restrict__ encw2T, int* __restrict__ deg, int N) {
    int r = blockIdx.y;
    if (r == 25) {                       // zero deg (runs before k_fill)
        int i = blockIdx.x * blockDim.x + threadIdx.x;
        if (i < N) deg[i] = 0;
        return;
    }
    const float* src; bf16* dst; int K, Nout;
    if (r < 12) {
        int l = r / 3, sel = r % 3;
        src = (sel == 0 ? wq : sel == 1 ? wk : wv) + (size_t)l * D * D;
        dst = wqkvT + (size_t)l * 3 * D * D + (size_t)sel * D * D;
        K = D; Nout = D;
    } else if (r < 16) {
        int l = r - 12;
        src = wo + (size_t)l * D * D; dst = woT + (size_t)l * D * D; K = D; Nout = D;
    } else if (r < 20) {
        int l = r - 16;
        src = w1 + (size_t)l * D * DFF; dst = w1T + (size_t)l * D * DFF; K = D; Nout = DFF;
    } else if (r < 24) {
        int l = r - 20;
        src = w2 + (size_t)l * DFF * D; dst = w2T + (size_t)l * DFF * D; K = DFF; Nout = D;
    } else {
        src = encw2; dst = encw2T; K = D; Nout = D;
    }
    int total = K * Nout;
    int i = blockIdx.x * blockDim.x + threadIdx.x;
    if (i >= total) return;
    int k = i / Nout, j = i % Nout;
    dst[(size_t)j * K + k] = __float2bfloat16(src[i]);
}

// helper: load this wave's 4 A-fragments (16 rows x 128 cols) from global
__device__ __forceinline__ void load_afrag(const bf16* A, int arow, int quad,
                                           int N, bf16x8* afr) {
    const bf16* ab = A + (size_t)arow * D + quad * 8;
#pragma unroll
    for (int i = 0; i < 4; i++) {
        uint4 v = make_uint4(0u, 0u, 0u, 0u);
        if (arow < N) v = *(const uint4*)(ab + i * 32);
        afr[i] = *(bf16x8*)&v;
    }
}

// ---------------- bf16 MFMA GEMM, 64 rows x 128 cols, K=128, 1 barrier ------
// OPs: 2 RES_LN (wo+ln2), 5 BIAS_LN (encode+ln1_0)
template<int OP>
__global__ __launch_bounds__(256) void k_gemm(
        const bf16* __restrict__ A, const bf16* __restrict__ Bt,
        const float* __restrict__ bias,
        const float* __restrict__ lns, const float* __restrict__ lnb,
        float* x, bf16* outB, int N) {
    __shared__ alignas(16) bf16 Wsm[128][AP];    // 33.8 KB -> 4 blocks/CU
    int m0 = blockIdx.x * BM;
    int t = threadIdx.x;
    int wave = t >> 6, lane = t & 63;
    int quad = lane >> 4, l16 = lane & 15;
    int wm = wave * 16;

    bf16x8 afr[4];
    load_afrag(A, m0 + wm + l16, quad, N, afr);
#pragma unroll
    for (int it = 0; it < 8; it++) {
        int ci = it * 256 + t;
        int rr = ci >> 4, cc = (ci & 15) * 8;
        *(uint4*)&Wsm[rr][cc] = *(const uint4*)(Bt + (size_t)rr * D + cc);
    }
    __syncthreads();

    f32x4 acc[8];
#pragma unroll
    for (int j = 0; j < 8; j++) acc[j] = (f32x4){0.f, 0.f, 0.f, 0.f};
#pragma unroll
    for (int i = 0; i < 4; i++) {
#pragma unroll
        for (int j = 0; j < 8; j++) {
            bf16x8 bfr = *(const bf16x8*)&Wsm[j * 16 + l16][i * 32 + quad * 8];
            acc[j] = __builtin_amdgcn_mfma_f32_16x16x32_bf16(afr[i], bfr, acc[j], 0, 0, 0);
        }
    }

    int rowb = m0 + wm + quad * 4;
    float bv[8];
    if (OP == 5) {
#pragma unroll
        for (int j = 0; j < 8; j++) bv[j] = bias[j * 16 + l16];
    }
#pragma unroll
    for (int j = 0; j < 8; j++) {
        int col = j * 16 + l16;
#pragma unroll
        for (int r = 0; r < 4; r++) {
            int gr = rowb + r;
            if (gr >= N) continue;
            float val = acc[j][r];
            if (OP == 5) val += bv[j];
            if (OP == 2) val += x[(size_t)gr * D + col];
            acc[j][r] = val;
        }
    }
    float lsv[8], lbv[8];
#pragma unroll
    for (int j = 0; j < 8; j++) {
        lsv[j] = lns[j * 16 + l16];
        lbv[j] = lnb[j * 16 + l16];
    }
#pragma unroll
    for (int r = 0; r < 4; r++) {
        float s1 = 0.f, s2 = 0.f;
#pragma unroll
        for (int j = 0; j < 8; j++) {
            float v = acc[j][r];
            s1 += v; s2 += v * v;
        }
        s1 += __shfl_xor(s1, 1, 64);  s2 += __shfl_xor(s2, 1, 64);
        s1 += __shfl_xor(s1, 2, 64);  s2 += __shfl_xor(s2, 2, 64);
        s1 += __shfl_xor(s1, 4, 64);  s2 += __shfl_xor(s2, 4, 64);
        s1 += __shfl_xor(s1, 8, 64);  s2 += __shfl_xor(s2, 8, 64);
        float mu = s1 * (1.f / 128.f);
        float var = s2 * (1.f / 128.f) - mu * mu;
        float rinv = rsqrtf(fmaxf(var, 0.f) + 1e-5f);
        int gr = rowb + r;
        if (gr >= N) continue;
#pragma unroll
        for (int j = 0; j < 8; j++) {
            int col = j * 16 + l16;
            float v = acc[j][r];
            x[(size_t)gr * D + col] = v;
            outB[(size_t)gr * D + col] =
                __float2bfloat16((v - mu) * rinv * lsv[j] + lbv[j]);
        }
    }
}

// ---------------- fused QKV: A-frags in regs, weight tile in LDS ------------
__global__ __launch_bounds__(256) void k_qkv(
        const bf16* __restrict__ hb, const bf16* __restrict__ wqkvT,
        bf16* __restrict__ qb, bf16* __restrict__ kvb, int N) {
    __shared__ alignas(16) bf16 Wsm[128][AP];
    int m0 = blockIdx.x * BM;
    int t = threadIdx.x;
    int wave = t >> 6, lane = t & 63;
    int quad = lane >> 4, l16 = lane & 15;
    int wm = wave * 16;

    bf16x8 afr[4];
    load_afrag(hb, m0 + wm + l16, quad, N, afr);

    for (int y = 0; y < 3; y++) {
        const bf16* W = wqkvT + (size_t)y * D * D;
#pragma unroll
        for (int it = 0; it < 8; it++) {
            int ci = it * 256 + t;
            int rr = ci >> 4, cc = (ci & 15) * 8;
            *(uint4*)&Wsm[rr][cc] = *(const uint4*)(W + (size_t)rr * D + cc);
        }
        __syncthreads();

        f32x4 acc[8];
#pragma unroll
        for (int j = 0; j < 8; j++) acc[j] = (f32x4){0.f, 0.f, 0.f, 0.f};
#pragma unroll
        for (int i = 0; i < 4; i++) {
#pragma unroll
            for (int j = 0; j < 8; j++) {
                bf16x8 bfr = *(const bf16x8*)&Wsm[j * 16 + l16][i * 32 + quad * 8];
                acc[j] = __builtin_amdgcn_mfma_f32_16x16x32_bf16(afr[i], bfr, acc[j], 0, 0, 0);
            }
        }
        int rowb = m0 + wm + quad * 4;
#pragma unroll
        for (int j = 0; j < 8; j++) {
            int col = j * 16 + l16;
#pragma unroll
            for (int r = 0; r < 4; r++) {
                int gr = rowb + r;
                if (gr >= N) continue;
                float val = acc[j][r];
                if (y == 0) qb[(size_t)gr * D + col] = __float2bfloat16(val * QSCALE_L2E);
                else kvb[((size_t)gr * D + col) * 2 + (y - 1)] = __float2bfloat16(val);
            }
        }
        if (y < 2) __syncthreads();
    }
}

// ---------------- fused FFN: x += relu(hb@w1+b1)@w2 + b2; then LN or DECODE -
// MODE 0: x store + LN1next -> outB.  MODE 1 (last layer): fused decoder —
// out = relu(xrow@dec_w1+db1)@dec_w2+db2, no x store (x dead afterwards).
template<int MODE>
__global__ __launch_bounds__(256) void k_ffn(
        const bf16* __restrict__ hb, const bf16* __restrict__ w1T,
        const float* __restrict__ b1,
        const bf16* __restrict__ w2T, const float* __restrict__ b2,
        const float* __restrict__ lns, const float* __restrict__ lnb,
        const float* __restrict__ dw1, const float* __restrict__ db1,
        const float* __restrict__ dw2, const float* __restrict__ db2,
        float* x, bf16* outB, float* out, int N) {
    __shared__ alignas(16) bf16 Wsm[128][AP];    // 33.8 KB (W1c / W2c)
    __shared__ alignas(16) bf16 Hsm[64][AP];     // 16.9 KB
    int m0 = blockIdx.x * 64;
    int t = threadIdx.x;
    int wave = t >> 6, lane = t & 63;
    int quad = lane >> 4, l16 = lane & 15;
    int wm = wave * 16;

    bf16x8 afr[4];
    load_afrag(hb, m0 + wm + l16, quad, N, afr);
#pragma unroll
    for (int it = 0; it < 8; it++) {
        int ci = it * 256 + t;
        int rr = ci >> 4, cc = (ci & 15) * 8;
        *(uint4*)&Wsm[rr][cc] = *(const uint4*)(w1T + (size_t)rr * D + cc);
    }
    __syncthreads();

    f32x4 acc2[8];
#pragma unroll
    for (int j = 0; j < 8; j++) acc2[j] = (f32x4){0.f, 0.f, 0.f, 0.f};

    for (int c = 0; c < 4; c++) {
        f32x4 accP[8];
#pragma unroll
        for (int j = 0; j < 8; j++) accP[j] = (f32x4){0.f, 0.f, 0.f, 0.f};
#pragma unroll
        for (int i = 0; i < 4; i++) {
#pragma unroll
            for (int j = 0; j < 8; j++) {
                bf16x8 bfr = *(const bf16x8*)&Wsm[j * 16 + l16][i * 32 + quad * 8];
                accP[j] = __builtin_amdgcn_mfma_f32_16x16x32_bf16(afr[i], bfr, accP[j], 0, 0, 0);
            }
        }
        __syncthreads();
#pragma unroll
        for (int it = 0; it < 8; it++) {
            int ci = it * 256 + t;
            int rr = ci >> 4, cc = (ci & 15) * 8;
            *(uint4*)&Wsm[rr][cc] = *(const uint4*)(w2T + (size_t)rr * DFF + c * 128 + cc);
        }
        {
            float bv[8];
#pragma unroll
            for (int j = 0; j < 8; j++) bv[j] = b1[c * 128 + j * 16 + l16];
            int rw = wm + quad * 4;
#pragma unroll
            for (int j = 0; j < 8; j++) {
                int col = j * 16 + l16;
#pragma unroll
                for (int r = 0; r < 4; r++)
                    Hsm[rw + r][col] = __float2bfloat16(fmaxf(accP[j][r] + bv[j], 0.f));
            }
        }
        __syncthreads();
#pragma unroll
        for (int ks = 0; ks < 4; ks++) {
            bf16x8 af2 = *(const bf16x8*)&Hsm[wm + l16][ks * 32 + quad * 8];
#pragma unroll
            for (int j = 0; j < 8; j++) {
                bf16x8 bfr = *(const bf16x8*)&Wsm[j * 16 + l16][ks * 32 + quad * 8];
                acc2[j] = __builtin_amdgcn_mfma_f32_16x16x32_bf16(af2, bfr, acc2[j], 0, 0, 0);
            }
        }
        if (c < 3) {
            __syncthreads();
#pragma unroll
            for (int it = 0; it < 8; it++) {
                int ci = it * 256 + t;
                int rr = ci >> 4, cc = (ci & 15) * 8;
                *(uint4*)&Wsm[rr][cc] =
                    *(const uint4*)(w1T + (size_t)((c + 1) * 128 + rr) * D + cc);
            }
            __syncthreads();
        }
    }

    // epilogue: acc2 = FFN out + b2 + x (residual)
    int rowb = m0 + wm + quad * 4;
    float bv[8];
#pragma unroll
    for (int j = 0; j < 8; j++) bv[j] = b2[j * 16 + l16];
#pragma unroll
    for (int j = 0; j < 8; j++) {
        int col = j * 16 + l16;
#pragma unroll
        for (int r = 0; r < 4; r++) {
            int gr = rowb + r;
            if (gr >= N) continue;
            acc2[j][r] += bv[j] + x[(size_t)gr * D + col];
        }
    }
    if (MODE == 1) {
        // fused decoder: per row, y_c = relu(sum_col xrow*dw1[col][c] + db1[c])
        float dw[8][3];
#pragma unroll
        for (int j = 0; j < 8; j++) {
            int col = j * 16 + l16;
#pragma unroll
            for (int cc3 = 0; cc3 < 3; cc3++) dw[j][cc3] = dw1[col * 3 + cc3];
        }
#pragma unroll
        for (int r = 0; r < 4; r++) {
            float s0 = 0.f, s1 = 0.f, s2 = 0.f;
#pragma unroll
            for (int j = 0; j < 8; j++) {
                float v = acc2[j][r];
                s0 += v * dw[j][0]; s1 += v * dw[j][1]; s2 += v * dw[j][2];
            }
            // reduce over the 16 l16 lanes (xor over lane bits 0-3 only)
            s0 += __shfl_xor(s0, 1, 64); s1 += __shfl_xor(s1, 1, 64); s2 += __shfl_xor(s2, 1, 64);
            s0 += __shfl_xor(s0, 2, 64); s1 += __shfl_xor(s1, 2, 64); s2 += __shfl_xor(s2, 2, 64);
            s0 += __shfl_xor(s0, 4, 64); s1 += __shfl_xor(s1, 4, 64); s2 += __shfl_xor(s2, 4, 64);
            s0 += __shfl_xor(s0, 8, 64); s1 += __shfl_xor(s1, 8, 64); s2 += __shfl_xor(s2, 8, 64);
            int gr = rowb + r;
            if (l16 == 0 && gr < N) {
                float t0 = fmaxf(s0 + db1[0], 0.f);
                float t1 = fmaxf(s1 + db1[1], 0.f);
                float t2 = fmaxf(s2 + db1[2], 0.f);
#pragma unroll
                for (int o = 0; o < 3; o++)
                    out[(size_t)gr * 3 + o] =
                        t0 * dw2[0 * 3 + o] + t1 * dw2[1 * 3 + o] + t2 * dw2[2 * 3 + o] + db2[o];
            }
        }
        return;
    }
    // MODE 0: store x + LN1next -> outB
    float lsv[8], lbv[8];
#pragma unroll
    for (int j = 0; j < 8; j++) {
        lsv[j] = lns[j * 16 + l16];
        lbv[j] = lnb[j * 16 + l16];
    }
#pragma unroll
    for (int r = 0; r < 4; r++) {
        float s1 = 0.f, s2 = 0.f;
#pragma unroll
        for (int j = 0; j < 8; j++) {
            float v = acc2[j][r];
            s1 += v; s2 += v * v;
        }
        s1 += __shfl_xor(s1, 1, 64);  s2 += __shfl_xor(s2, 1, 64);
        s1 += __shfl_xor(s1, 2, 64);  s2 += __shfl_xor(s2, 2, 64);
        s1 += __shfl_xor(s1, 4, 64);  s2 += __shfl_xor(s2, 4, 64);
        s1 += __shfl_xor(s1, 8, 64);  s2 += __shfl_xor(s2, 8, 64);
        float mu = s1 * (1.f / 128.f);
        float var = s2 * (1.f / 128.f) - mu * mu;
        float rinv = rsqrtf(fmaxf(var, 0.f) + 1e-5f);
        int gr = rowb + r;
        if (gr >= N) continue;
#pragma unroll
        for (int j = 0; j < 8; j++) {
            int col = j * 16 + l16;
            float v = acc2[j][r];
            x[(size_t)gr * D + col] = v;
            outB[(size_t)gr * D + col] = __float2bfloat16((v - mu) * rinv * lsv[j] + lbv[j]);
        }
    }
}

// ---------------- encoder stage 1: hb = bf16(relu(f@w1+b1)) ----------------
__global__ void k_enc1(const float* __restrict__ feat,
                       const float* __restrict__ w1, const float* __restrict__ b1,
                       bf16* __restrict__ hb, int N) {
    __shared__ float fsh[TN][DIN];
    int n0 = blockIdx.x * TN;
    int j = threadIdx.x;            // 0..127
    int nvalid = min(TN, N - n0);
    for (int idx = j; idx < TN * DIN; idx += 128) {
        int n = idx / DIN, i = idx % DIN;
        fsh[n][i] = (n < nvalid) ? feat[(n0 + n) * DIN + i] : 0.f;
    }
    __syncthreads();
    float bb = b1[j];
#pragma unroll
    for (int n = 0; n < TN; n++) {
        float a = bb;
#pragma unroll
        for (int i = 0; i < DIN; i++) a += fsh[n][i] * w1[i * D + j];
        if (n < nvalid) hb[(size_t)(n0 + n) * D + j] = __float2bfloat16(fmaxf(a, 0.f));
    }
}

// ---------------- attention: one wave per receiver (no LDS, no barrier) -----
__global__ __launch_bounds__(256) void k_attn(
        const bf16* __restrict__ qb, const uint* __restrict__ kvb,
        const int* __restrict__ deg, const int* __restrict__ eid,
        bf16* __restrict__ out, int N) {
    int wave = threadIdx.x >> 6, lane = threadIdx.x & 63;
    int r = blockIdx.x * 4 + wave;
    if (r >= N) return;
    int g = lane & 7;                    // dim group
    int h = (lane >> 3) & 3;             // head
    int slot = lane >> 5;                // edge slot 0..1
    int d0 = h * 32 + g * 4;
    uint2 qw = *(const uint2*)(qb + (size_t)r * D + d0);
    float4 qv;
    qv.x = __uint_as_float(qw.x << 16);
    qv.y = __uint_as_float(qw.x & 0xFFFF0000u);
    qv.z = __uint_as_float(qw.y << 16);
    qv.w = __uint_as_float(qw.y & 0xFFFF0000u);
    int cnt = min(deg[r], MAXDEG);
    const int* row = eid + (size_t)r * MAXDEG;
    float l = 0.f, a0 = 0.f, a1 = 0.f, a2 = 0.f, a3 = 0.f;
    for (int base = 0; base < cnt; base += 4) {
        int eiA = base + slot, eiB = base + 2 + slot;
        bool vA = eiA < cnt, vB = eiB < cnt;
        int sA = vA ? row[eiA] : 0;
        int sB = vB ? row[eiB] : 0;
        uint4 wA = *(const uint4*)(kvb + (size_t)sA * D + d0);
        uint4 wB = *(const uint4*)(kvb + (size_t)sB * D + d0);
        {
            float k0 = __uint_as_float(wA.x << 16), v0 = __uint_as_float(wA.x & 0xFFFF0000u);
            float k1 = __uint_as_float(wA.y << 16), v1 = __uint_as_float(wA.y & 0xFFFF0000u);
            float k2 = __uint_as_float(wA.z << 16), v2 = __uint_as_float(wA.z & 0xFFFF0000u);
            float k3 = __uint_as_float(wA.w << 16), v3 = __uint_as_float(wA.w & 0xFFFF0000u);
            float p = qv.x * k0 + qv.y * k1 + qv.z * k2 + qv.w * k3;
            p += __shfl_xor(p, 1, 64);
            p += __shfl_xor(p, 2, 64);
            p += __shfl_xor(p, 4, 64);
            float e = vA ? exp2f(p) : 0.f;
            l += e;
            a0 += e * v0; a1 += e * v1; a2 += e * v2; a3 += e * v3;
        }
        {
            float k0 = __uint_as_float(wB.x << 16), v0 = __uint_as_float(wB.x & 0xFFFF0000u);
            float k1 = __uint_as_float(wB.y << 16), v1 = __uint_as_float(wB.y & 0xFFFF0000u);
            float k2 = __uint_as_float(wB.z << 16), v2 = __uint_as_float(wB.z & 0xFFFF0000u);
            float k3 = __uint_as_float(wB.w << 16), v3 = __uint_as_float(wB.w & 0xFFFF0000u);
            float p = qv.x * k0 + qv.y * k1 + qv.z * k2 + qv.w * k3;
            p += __shfl_xor(p, 1, 64);
            p += __shfl_xor(p, 2, 64);
            p += __shfl_xor(p, 4, 64);
            float e = vB ? exp2f(p) : 0.f;
            l += e;
            a0 += e * v0; a1 += e * v1; a2 += e * v2; a3 += e * v3;
        }
    }
    l  += __shfl_xor(l, 32, 64);
    a0 += __shfl_xor(a0, 32, 64);
    a1 += __shfl_xor(a1, 32, 64);
    a2 += __shfl_xor(a2, 32, 64);
    a3 += __shfl_xor(a3, 32, 64);
    if (lane < 32) {
        float inv = 1.f / (l + 1e-9f);
        bf16 o[4];
        o[0] = __float2bfloat16(a0 * inv);
        o[1] = __float2bfloat16(a1 * inv);
        o[2] = __float2bfloat16(a2 * inv);
        o[3] = __float2bfloat16(a3 * inv);
        *(uint2*)(out + (size_t)r * D + d0) = *(uint2*)o;
    }
}

extern "C" void kernel_launch(void* const* d_in, const int* in_sizes, int n_in,
                              void* d_out, int out_size, void* d_ws, size_t ws_size,
                              hipStream_t stream) {
    const float* feat    = (const float*)d_in[0];
    const int*   senders = (const int*)d_in[1];
    const int*   recv    = (const int*)d_in[2];
    const float* enc_w1  = (const float*)d_in[3];
    const float* enc_b1  = (const float*)d_in[4];
    const float* enc_w2  = (const float*)d_in[5];
    const float* enc_b2  = (const float*)d_in[6];
    const float* wq      = (const float*)d_in[7];
    const float* wk      = (const float*)d_in[8];
    const float* wv      = (const float*)d_in[9];
    const float* wo      = (const float*)d_in[10];
    const float* ln1_s   = (const float*)d_in[11];
    const float* ln1_b   = (const float*)d_in[12];
    const float* ffn_w1  = (const float*)d_in[13];
    const float* ffn_b1  = (const float*)d_in[14];
    const float* ffn_w2  = (const float*)d_in[15];
    const float* ffn_b2  = (const float*)d_in[16];
    const float* ln2_s   = (const float*)d_in[17];
    const float* ln2_b   = (const float*)d_in[18];
    const float* dec_w1  = (const float*)d_in[19];
    const float* dec_b1  = (const float*)d_in[20];
    const float* dec_w2  = (const float*)d_in[21];
    const float* dec_b2  = (const float*)d_in[22];

    int N = in_sizes[0] / DIN;
    int E = in_sizes[1];

    // workspace layout
    char* p = (char*)d_ws;
    float* x   = (float*)p;  p += (size_t)N * D * 4;        // residual fp32
    bf16*  qb  = (bf16*)p;   p += (size_t)N * D * 2;        // q bf16 (pre-scaled)
    bf16*  kvb = (bf16*)p;   p += (size_t)N * D * 2 * 2;    // (k,v) bf16 interleaved
    bf16*  hb  = (bf16*)p;   p += (size_t)N * D * 2;        // LN out / attn out bf16
    int* deg   = (int*)p;    p += (size_t)N * 4;
    int* eid   = (int*)p;    p += (size_t)N * MAXDEG * 4;
    bf16* wqkvT  = (bf16*)p; p += (size_t)4 * 3 * D * D * 2;
    bf16* woT    = (bf16*)p; p += (size_t)4 * D * D * 2;
    bf16* w1T    = (bf16*)p; p += (size_t)4 * D * DFF * 2;
    bf16* w2T    = (bf16*)p; p += (size_t)4 * DFF * D * 2;
    bf16* encw2T = (bf16*)p; p += (size_t)D * D * 2;

    int gm = (N + BM - 1) / BM;   // 782

    k_wt<<<dim3(256, 26), 256, 0, stream>>>(wq, wk, wv, wo, ffn_w1, ffn_w2, enc_w2,
                                            wqkvT, woT, w1T, w2T, encw2T, deg, N);
    k_fill<<<(E + 255) / 256, 256, 0, stream>>>(recv, senders, deg, eid, E);
    k_enc1<<<(N + TN - 1) / TN, 128, 0, stream>>>(feat, enc_w1, enc_b1, hb, N);
    // x = hb @ enc_w2 + b2; hb = LN1_0(x)
    k_gemm<5><<<gm, 256, 0, stream>>>(hb, encw2T, enc_b2, ln1_s, ln1_b, x, hb, N);

    for (int l = 0; l < 4; l++) {
        k_qkv<<<gm, 256, 0, stream>>>(hb, wqkvT + (size_t)l * 3 * D * D, qb, kvb, N);
        k_attn<<<(N + 3) / 4, 256, 0, stream>>>(qb, (const uint*)kvb, deg, eid, hb, N);
        // x += hb @ wo; hb = LN2(x)
        k_gemm<2><<<gm, 256, 0, stream>>>(hb, woT + (size_t)l * D * D,
                                          nullptr, ln2_s + l * D, ln2_b + l * D,
                                          x, hb, N);
        // x += relu(hb@w1+b1)@w2 + b2; then LN1_{l+1} (l<3) or fused decode (l=3)
        if (l < 3)
            k_ffn<0><<<gm, 256, 0, stream>>>(hb, w1T + (size_t)l * D * DFF,
                                             ffn_b1 + l * DFF,
                                             w2T + (size_t)l * DFF * D, ffn_b2 + l * D,
                                             ln1_s + (l + 1) * D, ln1_b + (l + 1) * D,
                                             nullptr, nullptr, nullptr, nullptr,
                                             x, hb, nullptr, N);
        else
            k_ffn<1><<<gm, 256, 0, stream>>>(hb, w1T + (size_t)l * D * DFF,
                                             ffn_b1 + l * DFF,
                                             w2T + (size_t)l * DFF * D, ffn_b2 + l * D,
                                             nullptr, nullptr,
                                             dec_w1, dec_b1, dec_w2, dec_b2,
                                             x, nullptr, (float*)d_out, N);
    }
}

// Round 17
// 729.165 us; speedup vs baseline: 1.1783x; 1.0043x over previous
//
#include <hip/hip_runtime.h>
#include <hip/hip_bf16.h>
#include <math.h>

#define D     128
#define NHEAD 4
#define DH    32
#define DFF   512
#define DIN   16
#define MAXDEG 64
#define TN    16

typedef __attribute__((ext_vector_type(8))) short bf16x8;
typedef __attribute__((ext_vector_type(4))) float f32x4;
typedef __hip_bfloat16 bf16;

// 1/sqrt(32) * log2(e): q pre-scaled so attn weight = exp2(q.k)
#define QSCALE_L2E 0.2550348838f

// LDS row pad 132 bf16: C-layout scalar writes conflict-free (r9/r11).
// r10: register-prefetch of weight tiles spills — don't.
// r13: A-fragments in 16 VGPRs straight from global; best dense config.
// r14: wo+ffn mega-fusion REGRESSED — dense chain is latency-plateau'd.
// r16: dispatch/traffic elimination outside inner loops works (+22 µs).
// r17: attn 8-edge ILP (2 slots x 4-deep unroll) for memory-level parallelism.
#define AP 132
#define BM 64

// ---------------- CSR fill (deg zeroed by k_wt region 25) ----------------
__global__ void k_fill(const int* __restrict__ recv, const int* __restrict__ senders,
                       int* __restrict__ deg, int* __restrict__ eid, int E) {
    int e = blockIdx.x * blockDim.x + threadIdx.x;
    if (e >= E) return;
    int r = recv[e];
    int pos = atomicAdd(&deg[r], 1);
    if (pos < MAXDEG) eid[r * MAXDEG + pos] = senders[e];
}

// ---------------- weight transpose + bf16 convert + deg zero (26 regions) ----
__global__ void k_wt(const float* __restrict__ wq, const float* __restrict__ wk,
                     const float* __restrict__ wv, const float* __restrict__ wo,
                     const float* __restrict__ w1, const float* __restrict__ w2,
                     const float* __restrict__ encw2,
                     bf16* __restrict__ wqkvT, bf16* __restrict__ woT,
                     bf16* __restrict__ w1T, bf16* __restrict__ w2T,
                     bf16* __restrict__ encw2T, int* __restrict__ deg, int N) {
    int r = blockIdx.y;
    if (r == 25) {                       // zero deg (runs before k_fill)
        int i = blockIdx.x * blockDim.x + threadIdx.x;
        if (i < N) deg[i] = 0;
        return;
    }
    const float* src; bf16* dst; int K, Nout;
    if (r < 12) {
        int l = r / 3, sel = r % 3;
        src = (sel == 0 ? wq : sel == 1 ? wk : wv) + (size_t)l * D * D;
        dst = wqkvT + (size_t)l * 3 * D * D + (size_t)sel * D * D;
        K = D; Nout = D;
    } else if (r < 16) {
        int l = r - 12;
        src = wo + (size_t)l * D * D; dst = woT + (size_t)l * D * D; K = D; Nout = D;
    } else if (r < 20) {
        int l = r - 16;
        src = w1 + (size_t)l * D * DFF; dst = w1T + (size_t)l * D * DFF; K = D; Nout = DFF;
    } else if (r < 24) {
        int l = r - 20;
        src = w2 + (size_t)l * DFF * D; dst = w2T + (size_t)l * DFF * D; K = DFF; Nout = D;
    } else {
        src = encw2; dst = encw2T; K = D; Nout = D;
    }
    int total = K * Nout;
    int i = blockIdx.x * blockDim.x + threadIdx.x;
    if (i >= total) return;
    int k = i / Nout, j = i % Nout;
    dst[(size_t)j * K + k] = __float2bfloat16(src[i]);
}

// helper: load this wave's 4 A-fragments (16 rows x 128 cols) from global
__device__ __forceinline__ void load_afrag(const bf16* A, int arow, int quad,
                                           int N, bf16x8* afr) {
    const bf16* ab = A + (size_t)arow * D + quad * 8;
#pragma unroll
    for (int i = 0; i < 4; i++) {
        uint4 v = make_uint4(0u, 0u, 0u, 0u);
        if (arow < N) v = *(const uint4*)(ab + i * 32);
        afr[i] = *(bf16x8*)&v;
    }
}

// ---------------- bf16 MFMA GEMM, 64 rows x 128 cols, K=128, 1 barrier ------
// OPs: 2 RES_LN (wo+ln2), 5 BIAS_LN (encode+ln1_0)
template<int OP>
__global__ __launch_bounds__(256) void k_gemm(
        const bf16* __restrict__ A, const bf16* __restrict__ Bt,
        const float* __restrict__ bias,
        const float* __restrict__ lns, const float* __restrict__ lnb,
        float* x, bf16* outB, int N) {
    __shared__ alignas(16) bf16 Wsm[128][AP];    // 33.8 KB -> 4 blocks/CU
    int m0 = blockIdx.x * BM;
    int t = threadIdx.x;
    int wave = t >> 6, lane = t & 63;
    int quad = lane >> 4, l16 = lane & 15;
    int wm = wave * 16;

    bf16x8 afr[4];
    load_afrag(A, m0 + wm + l16, quad, N, afr);
#pragma unroll
    for (int it = 0; it < 8; it++) {
        int ci = it * 256 + t;
        int rr = ci >> 4, cc = (ci & 15) * 8;
        *(uint4*)&Wsm[rr][cc] = *(const uint4*)(Bt + (size_t)rr * D + cc);
    }
    __syncthreads();

    f32x4 acc[8];
#pragma unroll
    for (int j = 0; j < 8; j++) acc[j] = (f32x4){0.f, 0.f, 0.f, 0.f};
#pragma unroll
    for (int i = 0; i < 4; i++) {
#pragma unroll
        for (int j = 0; j < 8; j++) {
            bf16x8 bfr = *(const bf16x8*)&Wsm[j * 16 + l16][i * 32 + quad * 8];
            acc[j] = __builtin_amdgcn_mfma_f32_16x16x32_bf16(afr[i], bfr, acc[j], 0, 0, 0);
        }
    }

    int rowb = m0 + wm + quad * 4;
    float bv[8];
    if (OP == 5) {
#pragma unroll
        for (int j = 0; j < 8; j++) bv[j] = bias[j * 16 + l16];
    }
#pragma unroll
    for (int j = 0; j < 8; j++) {
        int col = j * 16 + l16;
#pragma unroll
        for (int r = 0; r < 4; r++) {
            int gr = rowb + r;
            if (gr >= N) continue;
            float val = acc[j][r];
            if (OP == 5) val += bv[j];
            if (OP == 2) val += x[(size_t)gr * D + col];
            acc[j][r] = val;
        }
    }
    float lsv[8], lbv[8];
#pragma unroll
    for (int j = 0; j < 8; j++) {
        lsv[j] = lns[j * 16 + l16];
        lbv[j] = lnb[j * 16 + l16];
    }
#pragma unroll
    for (int r = 0; r < 4; r++) {
        float s1 = 0.f, s2 = 0.f;
#pragma unroll
        for (int j = 0; j < 8; j++) {
            float v = acc[j][r];
            s1 += v; s2 += v * v;
        }
        s1 += __shfl_xor(s1, 1, 64);  s2 += __shfl_xor(s2, 1, 64);
        s1 += __shfl_xor(s1, 2, 64);  s2 += __shfl_xor(s2, 2, 64);
        s1 += __shfl_xor(s1, 4, 64);  s2 += __shfl_xor(s2, 4, 64);
        s1 += __shfl_xor(s1, 8, 64);  s2 += __shfl_xor(s2, 8, 64);
        float mu = s1 * (1.f / 128.f);
        float var = s2 * (1.f / 128.f) - mu * mu;
        float rinv = rsqrtf(fmaxf(var, 0.f) + 1e-5f);
        int gr = rowb + r;
        if (gr >= N) continue;
#pragma unroll
        for (int j = 0; j < 8; j++) {
            int col = j * 16 + l16;
            float v = acc[j][r];
            x[(size_t)gr * D + col] = v;
            outB[(size_t)gr * D + col] =
                __float2bfloat16((v - mu) * rinv * lsv[j] + lbv[j]);
        }
    }
}

// ---------------- fused QKV: A-frags in regs, weight tile in LDS ------------
__global__ __launch_bounds__(256) void k_qkv(
        const bf16* __restrict__ hb, const bf16* __restrict__ wqkvT,
        bf16* __restrict__ qb, bf16* __restrict__ kvb, int N) {
    __shared__ alignas(16) bf16 Wsm[128][AP];
    int m0 = blockIdx.x * BM;
    int t = threadIdx.x;
    int wave = t >> 6, lane = t & 63;
    int quad = lane >> 4, l16 = lane & 15;
    int wm = wave * 16;

    bf16x8 afr[4];
    load_afrag(hb, m0 + wm + l16, quad, N, afr);

    for (int y = 0; y < 3; y++) {
        const bf16* W = wqkvT + (size_t)y * D * D;
#pragma unroll
        for (int it = 0; it < 8; it++) {
            int ci = it * 256 + t;
            int rr = ci >> 4, cc = (ci & 15) * 8;
            *(uint4*)&Wsm[rr][cc] = *(const uint4*)(W + (size_t)rr * D + cc);
        }
        __syncthreads();

        f32x4 acc[8];
#pragma unroll
        for (int j = 0; j < 8; j++) acc[j] = (f32x4){0.f, 0.f, 0.f, 0.f};
#pragma unroll
        for (int i = 0; i < 4; i++) {
#pragma unroll
            for (int j = 0; j < 8; j++) {
                bf16x8 bfr = *(const bf16x8*)&Wsm[j * 16 + l16][i * 32 + quad * 8];
                acc[j] = __builtin_amdgcn_mfma_f32_16x16x32_bf16(afr[i], bfr, acc[j], 0, 0, 0);
            }
        }
        int rowb = m0 + wm + quad * 4;
#pragma unroll
        for (int j = 0; j < 8; j++) {
            int col = j * 16 + l16;
#pragma unroll
            for (int r = 0; r < 4; r++) {
                int gr = rowb + r;
                if (gr >= N) continue;
                float val = acc[j][r];
                if (y == 0) qb[(size_t)gr * D + col] = __float2bfloat16(val * QSCALE_L2E);
                else kvb[((size_t)gr * D + col) * 2 + (y - 1)] = __float2bfloat16(val);
            }
        }
        if (y < 2) __syncthreads();
    }
}

// ---------------- fused FFN: x += relu(hb@w1+b1)@w2 + b2; then LN or DECODE -
template<int MODE>
__global__ __launch_bounds__(256) void k_ffn(
        const bf16* __restrict__ hb, const bf16* __restrict__ w1T,
        const float* __restrict__ b1,
        const bf16* __restrict__ w2T, const float* __restrict__ b2,
        const float* __restrict__ lns, const float* __restrict__ lnb,
        const float* __restrict__ dw1, const float* __restrict__ db1,
        const float* __restrict__ dw2, const float* __restrict__ db2,
        float* x, bf16* outB, float* out, int N) {
    __shared__ alignas(16) bf16 Wsm[128][AP];    // 33.8 KB (W1c / W2c)
    __shared__ alignas(16) bf16 Hsm[64][AP];     // 16.9 KB
    int m0 = blockIdx.x * 64;
    int t = threadIdx.x;
    int wave = t >> 6, lane = t & 63;
    int quad = lane >> 4, l16 = lane & 15;
    int wm = wave * 16;

    bf16x8 afr[4];
    load_afrag(hb, m0 + wm + l16, quad, N, afr);
#pragma unroll
    for (int it = 0; it < 8; it++) {
        int ci = it * 256 + t;
        int rr = ci >> 4, cc = (ci & 15) * 8;
        *(uint4*)&Wsm[rr][cc] = *(const uint4*)(w1T + (size_t)rr * D + cc);
    }
    __syncthreads();

    f32x4 acc2[8];
#pragma unroll
    for (int j = 0; j < 8; j++) acc2[j] = (f32x4){0.f, 0.f, 0.f, 0.f};

    for (int c = 0; c < 4; c++) {
        f32x4 accP[8];
#pragma unroll
        for (int j = 0; j < 8; j++) accP[j] = (f32x4){0.f, 0.f, 0.f, 0.f};
#pragma unroll
        for (int i = 0; i < 4; i++) {
#pragma unroll
            for (int j = 0; j < 8; j++) {
                bf16x8 bfr = *(const bf16x8*)&Wsm[j * 16 + l16][i * 32 + quad * 8];
                accP[j] = __builtin_amdgcn_mfma_f32_16x16x32_bf16(afr[i], bfr, accP[j], 0, 0, 0);
            }
        }
        __syncthreads();
#pragma unroll
        for (int it = 0; it < 8; it++) {
            int ci = it * 256 + t;
            int rr = ci >> 4, cc = (ci & 15) * 8;
            *(uint4*)&Wsm[rr][cc] = *(const uint4*)(w2T + (size_t)rr * DFF + c * 128 + cc);
        }
        {
            float bv[8];
#pragma unroll
            for (int j = 0; j < 8; j++) bv[j] = b1[c * 128 + j * 16 + l16];
            int rw = wm + quad * 4;
#pragma unroll
            for (int j = 0; j < 8; j++) {
                int col = j * 16 + l16;
#pragma unroll
                for (int r = 0; r < 4; r++)
                    Hsm[rw + r][col] = __float2bfloat16(fmaxf(accP[j][r] + bv[j], 0.f));
            }
        }
        __syncthreads();
#pragma unroll
        for (int ks = 0; ks < 4; ks++) {
            bf16x8 af2 = *(const bf16x8*)&Hsm[wm + l16][ks * 32 + quad * 8];
#pragma unroll
            for (int j = 0; j < 8; j++) {
                bf16x8 bfr = *(const bf16x8*)&Wsm[j * 16 + l16][ks * 32 + quad * 8];
                acc2[j] = __builtin_amdgcn_mfma_f32_16x16x32_bf16(af2, bfr, acc2[j], 0, 0, 0);
            }
        }
        if (c < 3) {
            __syncthreads();
#pragma unroll
            for (int it = 0; it < 8; it++) {
                int ci = it * 256 + t;
                int rr = ci >> 4, cc = (ci & 15) * 8;
                *(uint4*)&Wsm[rr][cc] =
                    *(const uint4*)(w1T + (size_t)((c + 1) * 128 + rr) * D + cc);
            }
            __syncthreads();
        }
    }

    int rowb = m0 + wm + quad * 4;
    float bv[8];
#pragma unroll
    for (int j = 0; j < 8; j++) bv[j] = b2[j * 16 + l16];
#pragma unroll
    for (int j = 0; j < 8; j++) {
        int col = j * 16 + l16;
#pragma unroll
        for (int r = 0; r < 4; r++) {
            int gr = rowb + r;
            if (gr >= N) continue;
            acc2[j][r] += bv[j] + x[(size_t)gr * D + col];
        }
    }
    if (MODE == 1) {
        float dw[8][3];
#pragma unroll
        for (int j = 0; j < 8; j++) {
            int col = j * 16 + l16;
#pragma unroll
            for (int cc3 = 0; cc3 < 3; cc3++) dw[j][cc3] = dw1[col * 3 + cc3];
        }
#pragma unroll
        for (int r = 0; r < 4; r++) {
            float s0 = 0.f, s1 = 0.f, s2 = 0.f;
#pragma unroll
            for (int j = 0; j < 8; j++) {
                float v = acc2[j][r];
                s0 += v * dw[j][0]; s1 += v * dw[j][1]; s2 += v * dw[j][2];
            }
            s0 += __shfl_xor(s0, 1, 64); s1 += __shfl_xor(s1, 1, 64); s2 += __shfl_xor(s2, 1, 64);
            s0 += __shfl_xor(s0, 2, 64); s1 += __shfl_xor(s1, 2, 64); s2 += __shfl_xor(s2, 2, 64);
            s0 += __shfl_xor(s0, 4, 64); s1 += __shfl_xor(s1, 4, 64); s2 += __shfl_xor(s2, 4, 64);
            s0 += __shfl_xor(s0, 8, 64); s1 += __shfl_xor(s1, 8, 64); s2 += __shfl_xor(s2, 8, 64);
            int gr = rowb + r;
            if (l16 == 0 && gr < N) {
                float t0 = fmaxf(s0 + db1[0], 0.f);
                float t1 = fmaxf(s1 + db1[1], 0.f);
                float t2 = fmaxf(s2 + db1[2], 0.f);
#pragma unroll
                for (int o = 0; o < 3; o++)
                    out[(size_t)gr * 3 + o] =
                        t0 * dw2[0 * 3 + o] + t1 * dw2[1 * 3 + o] + t2 * dw2[2 * 3 + o] + db2[o];
            }
        }
        return;
    }
    float lsv[8], lbv[8];
#pragma unroll
    for (int j = 0; j < 8; j++) {
        lsv[j] = lns[j * 16 + l16];
        lbv[j] = lnb[j * 16 + l16];
    }
#pragma unroll
    for (int r = 0; r < 4; r++) {
        float s1 = 0.f, s2 = 0.f;
#pragma unroll
        for (int j = 0; j < 8; j++) {
            float v = acc2[j][r];
            s1 += v; s2 += v * v;
        }
        s1 += __shfl_xor(s1, 1, 64);  s2 += __shfl_xor(s2, 1, 64);
        s1 += __shfl_xor(s1, 2, 64);  s2 += __shfl_xor(s2, 2, 64);
        s1 += __shfl_xor(s1, 4, 64);  s2 += __shfl_xor(s2, 4, 64);
        s1 += __shfl_xor(s1, 8, 64);  s2 += __shfl_xor(s2, 8, 64);
        float mu = s1 * (1.f / 128.f);
        float var = s2 * (1.f / 128.f) - mu * mu;
        float rinv = rsqrtf(fmaxf(var, 0.f) + 1e-5f);
        int gr = rowb + r;
        if (gr >= N) continue;
#pragma unroll
        for (int j = 0; j < 8; j++) {
            int col = j * 16 + l16;
            float v = acc2[j][r];
            x[(size_t)gr * D + col] = v;
            outB[(size_t)gr * D + col] = __float2bfloat16((v - mu) * rinv * lsv[j] + lbv[j]);
        }
    }
}

// ---------------- encoder stage 1: hb = bf16(relu(f@w1+b1)) ----------------
__global__ void k_enc1(const float* __restrict__ feat,
                       const float* __restrict__ w1, const float* __restrict__ b1,
                       bf16* __restrict__ hb, int N) {
    __shared__ float fsh[TN][DIN];
    int n0 = blockIdx.x * TN;
    int j = threadIdx.x;            // 0..127
    int nvalid = min(TN, N - n0);
    for (int idx = j; idx < TN * DIN; idx += 128) {
        int n = idx / DIN, i = idx % DIN;
        fsh[n][i] = (n < nvalid) ? feat[(n0 + n) * DIN + i] : 0.f;
    }
    __syncthreads();
    float bb = b1[j];
#pragma unroll
    for (int n = 0; n < TN; n++) {
        float a = bb;
#pragma unroll
        for (int i = 0; i < DIN; i++) a += fsh[n][i] * w1[i * D + j];
        if (n < nvalid) hb[(size_t)(n0 + n) * D + j] = __float2bfloat16(fmaxf(a, 0.f));
    }
}

// ---------------- attention: one wave per receiver, 8-edge ILP --------------
// slot = lane>>5 (2 slots); 4-deep unroll -> 8 index loads + 8 gathers in
// flight per iteration before any consumption.
__device__ __forceinline__ void attn_edge(uint4 w, bool v, float4 qv,
                                          float& l, float& a0, float& a1,
                                          float& a2, float& a3) {
    float k0 = __uint_as_float(w.x << 16), v0 = __uint_as_float(w.x & 0xFFFF0000u);
    float k1 = __uint_as_float(w.y << 16), v1 = __uint_as_float(w.y & 0xFFFF0000u);
    float k2 = __uint_as_float(w.z << 16), v2 = __uint_as_float(w.z & 0xFFFF0000u);
    float k3 = __uint_as_float(w.w << 16), v3 = __uint_as_float(w.w & 0xFFFF0000u);
    float p = qv.x * k0 + qv.y * k1 + qv.z * k2 + qv.w * k3;
    p += __shfl_xor(p, 1, 64);
    p += __shfl_xor(p, 2, 64);
    p += __shfl_xor(p, 4, 64);
    float e = v ? exp2f(p) : 0.f;
    l += e;
    a0 += e * v0; a1 += e * v1; a2 += e * v2; a3 += e * v3;
}

__global__ __launch_bounds__(256) void k_attn(
        const bf16* __restrict__ qb, const uint* __restrict__ kvb,
        const int* __restrict__ deg, const int* __restrict__ eid,
        bf16* __restrict__ out, int N) {
    int wave = threadIdx.x >> 6, lane = threadIdx.x & 63;
    int r = blockIdx.x * 4 + wave;
    if (r >= N) return;
    int g = lane & 7;                    // dim group
    int h = (lane >> 3) & 3;             // head
    int slot = lane >> 5;                // edge slot 0..1
    int d0 = h * 32 + g * 4;
    uint2 qw = *(const uint2*)(qb + (size_t)r * D + d0);
    float4 qv;
    qv.x = __uint_as_float(qw.x << 16);
    qv.y = __uint_as_float(qw.x & 0xFFFF0000u);
    qv.z = __uint_as_float(qw.y << 16);
    qv.w = __uint_as_float(qw.y & 0xFFFF0000u);
    int cnt = min(deg[r], MAXDEG);
    const int* row = eid + (size_t)r * MAXDEG;
    float l = 0.f, a0 = 0.f, a1 = 0.f, a2 = 0.f, a3 = 0.f;
    for (int base = 0; base < cnt; base += 8) {
        int ei[4];
        bool vv[4];
        int ss[4];
#pragma unroll
        for (int u = 0; u < 4; u++) {
            ei[u] = base + u * 2 + slot;
            vv[u] = ei[u] < cnt;
            ss[u] = vv[u] ? row[ei[u]] : 0;
        }
        uint4 w0 = *(const uint4*)(kvb + (size_t)ss[0] * D + d0);
        uint4 w1 = *(const uint4*)(kvb + (size_t)ss[1] * D + d0);
        uint4 w2 = *(const uint4*)(kvb + (size_t)ss[2] * D + d0);
        uint4 w3 = *(const uint4*)(kvb + (size_t)ss[3] * D + d0);
        attn_edge(w0, vv[0], qv, l, a0, a1, a2, a3);
        attn_edge(w1, vv[1], qv, l, a0, a1, a2, a3);
        attn_edge(w2, vv[2], qv, l, a0, a1, a2, a3);
        attn_edge(w3, vv[3], qv, l, a0, a1, a2, a3);
    }
    // combine the 2 edge slots (lane bit 5)
    l  += __shfl_xor(l, 32, 64);
    a0 += __shfl_xor(a0, 32, 64);
    a1 += __shfl_xor(a1, 32, 64);
    a2 += __shfl_xor(a2, 32, 64);
    a3 += __shfl_xor(a3, 32, 64);
    if (lane < 32) {
        float inv = 1.f / (l + 1e-9f);
        bf16 o[4];
        o[0] = __float2bfloat16(a0 * inv);
        o[1] = __float2bfloat16(a1 * inv);
        o[2] = __float2bfloat16(a2 * inv);
        o[3] = __float2bfloat16(a3 * inv);
        *(uint2*)(out + (size_t)r * D + d0) = *(uint2*)o;
    }
}

extern "C" void kernel_launch(void* const* d_in, const int* in_sizes, int n_in,
                              void* d_out, int out_size, void* d_ws, size_t ws_size,
                              hipStream_t stream) {
    const float* feat    = (const float*)d_in[0];
    const int*   senders = (const int*)d_in[1];
    const int*   recv    = (const int*)d_in[2];
    const float* enc_w1  = (const float*)d_in[3];
    const float* enc_b1  = (const float*)d_in[4];
    const float* enc_w2  = (const float*)d_in[5];
    const float* enc_b2  = (const float*)d_in[6];
    const float* wq      = (const float*)d_in[7];
    const float* wk      = (const float*)d_in[8];
    const float* wv      = (const float*)d_in[9];
    const float* wo      = (const float*)d_in[10];
    const float* ln1_s   = (const float*)d_in[11];
    const float* ln1_b   = (const float*)d_in[12];
    const float* ffn_w1  = (const float*)d_in[13];
    const float* ffn_b1  = (const float*)d_in[14];
    const float* ffn_w2  = (const float*)d_in[15];
    const float* ffn_b2  = (const float*)d_in[16];
    const float* ln2_s   = (const float*)d_in[17];
    const float* ln2_b   = (const float*)d_in[18];
    const float* dec_w1  = (const float*)d_in[19];
    const float* dec_b1  = (const float*)d_in[20];
    const float* dec_w2  = (const float*)d_in[21];
    const float* dec_b2  = (const float*)d_in[22];

    int N = in_sizes[0] / DIN;
    int E = in_sizes[1];

    // workspace layout
    char* p = (char*)d_ws;
    float* x   = (float*)p;  p += (size_t)N * D * 4;        // residual fp32
    bf16*  qb  = (bf16*)p;   p += (size_t)N * D * 2;        // q bf16 (pre-scaled)
    bf16*  kvb = (bf16*)p;   p += (size_t)N * D * 2 * 2;    // (k,v) bf16 interleaved
    bf16*  hb  = (bf16*)p;   p += (size_t)N * D * 2;        // LN out / attn out bf16
    int* deg   = (int*)p;    p += (size_t)N * 4;
    int* eid   = (int*)p;    p += (size_t)N * MAXDEG * 4;
    bf16* wqkvT  = (bf16*)p; p += (size_t)4 * 3 * D * D * 2;
    bf16* woT    = (bf16*)p; p += (size_t)4 * D * D * 2;
    bf16* w1T    = (bf16*)p; p += (size_t)4 * D * DFF * 2;
    bf16* w2T    = (bf16*)p; p += (size_t)4 * DFF * D * 2;
    bf16* encw2T = (bf16*)p; p += (size_t)D * D * 2;

    int gm = (N + BM - 1) / BM;   // 782

    k_wt<<<dim3(256, 26), 256, 0, stream>>>(wq, wk, wv, wo, ffn_w1, ffn_w2, enc_w2,
                                            wqkvT, woT, w1T, w2T, encw2T, deg, N);
    k_fill<<<(E + 255) / 256, 256, 0, stream>>>(recv, senders, deg, eid, E);
    k_enc1<<<(N + TN - 1) / TN, 128, 0, stream>>>(feat, enc_w1, enc_b1, hb, N);
    // x = hb @ enc_w2 + b2; hb = LN1_0(x)
    k_gemm<5><<<gm, 256, 0, stream>>>(hb, encw2T, enc_b2, ln1_s, ln1_b, x, hb, N);

    for (int l = 0; l < 4; l++) {
        k_qkv<<<gm, 256, 0, stream>>>(hb, wqkvT + (size_t)l * 3 * D * D, qb, kvb, N);
        k_attn<<<(N + 3) / 4, 256, 0, stream>>>(qb, (const uint*)kvb, deg, eid, hb, N);
        // x += hb @ wo; hb = LN2(x)
        k_gemm<2><<<gm, 256, 0, stream>>>(hb, woT + (size_t)l * D * D,
                                          nullptr, ln2_s + l * D, ln2_b + l * D,
                                          x, hb, N);
        // x += relu(hb@w1+b1)@w2 + b2; then LN1_{l+1} (l<3) or fused decode (l=3)
        if (l < 3)
            k_ffn<0><<<gm, 256, 0, stream>>>(hb, w1T + (size_t)l * D * DFF,
                                             ffn_b1 + l * DFF,
                                             w2T + (size_t)l * DFF * D, ffn_b2 + l * D,
                                             ln1_s + (l + 1) * D, ln1_b + (l + 1) * D,
                                             nullptr, nullptr, nullptr, nullptr,
                                             x, hb, nullptr, N);
        else
            k_ffn<1><<<gm, 256, 0, stream>>>(hb, w1T + (size_t)l * D * DFF,
                                             ffn_b1 + l * DFF,
                                             w2T + (size_t)l * DFF * D, ffn_b2 + l * D,
                                             nullptr, nullptr,
                                             dec_w1, dec_b1, dec_w2, dec_b2,
                                             x, nullptr, (float*)d_out, N);
    }
}